// Round 1
// baseline (749.260 us; speedup 1.0000x reference)
//
#include <hip/hip_runtime.h>
#include <hip/hip_bf16.h>
#include <cstdio>

// ---------------------------------------------------------------------------
// DeepONet fused pipeline, f32 baseline.
// Shapes: BATCH=2048, SENSOR=128, B_UNITS=1024, LORA=64, P=33409 (trunk params)
// params[b] = z[b] @ W2 ; trunk layer2/3 reformulated as GEMM over (i,k) outer
// product: h2 = tanh( (h1 (x) z | z) @ gathered(W2) ), K = 128*64 + 64 = 8256.
// ---------------------------------------------------------------------------

#define BM 64
#define BN 64
#define BK 16
#define LDP 33409
#define SPLITK 4
#define KSLICE 2064   // 8256 / 4, multiple of BK

// C[M,N](ldc) = act( A[M,K](lda) @ W[K,N](ldw, col offset col0) + bias )
template<int ACT>
__global__ __launch_bounds__(256)
void gemm_f32(const float* __restrict__ A, int lda,
              const float* __restrict__ W, int ldw, int col0,
              const float* __restrict__ bias,
              float* __restrict__ C, int ldc,
              int M, int N, int K)
{
    __shared__ float Ast[BK][BM];   // A tile, transposed: [k][row]
    __shared__ float Bs[BK][BN];
    const int tid = threadIdx.x;
    const int tx = tid & 15, ty = tid >> 4;
    const int bm = blockIdx.y * BM, bn = blockIdx.x * BN;
    const int ar = tid >> 2, aq = tid & 3;   // A staging: row, k-quad
    const int bk = tid >> 4, bq = tid & 15;  // B staging: k-row, n-quad
    const bool wvec = ((ldw & 3) == 0) && ((col0 & 3) == 0);
    float acc[4][4] = {};

    for (int k0 = 0; k0 < K; k0 += BK) {
        // ---- stage A (64 rows x 16 k), one float4 per thread
        float4 av = *(const float4*)&A[(size_t)(bm + ar) * lda + k0 + aq * 4];
        Ast[aq*4+0][ar] = av.x; Ast[aq*4+1][ar] = av.y;
        Ast[aq*4+2][ar] = av.z; Ast[aq*4+3][ar] = av.w;
        // ---- stage B (16 k x 64 n)
        const float* wrow = &W[(size_t)(k0 + bk) * ldw + col0 + bn + bq * 4];
        if (wvec) {
            float4 bv = *(const float4*)wrow;
            Bs[bk][bq*4+0] = bv.x; Bs[bk][bq*4+1] = bv.y;
            Bs[bk][bq*4+2] = bv.z; Bs[bk][bq*4+3] = bv.w;
        } else {
            Bs[bk][bq*4+0] = wrow[0]; Bs[bk][bq*4+1] = wrow[1];
            Bs[bk][bq*4+2] = wrow[2]; Bs[bk][bq*4+3] = wrow[3];
        }
        __syncthreads();
        #pragma unroll
        for (int kk = 0; kk < BK; ++kk) {
            float4 a4 = *(const float4*)&Ast[kk][ty * 4];
            float4 b4 = *(const float4*)&Bs[kk][tx * 4];
            acc[0][0] += a4.x*b4.x; acc[0][1] += a4.x*b4.y; acc[0][2] += a4.x*b4.z; acc[0][3] += a4.x*b4.w;
            acc[1][0] += a4.y*b4.x; acc[1][1] += a4.y*b4.y; acc[1][2] += a4.y*b4.z; acc[1][3] += a4.y*b4.w;
            acc[2][0] += a4.z*b4.x; acc[2][1] += a4.z*b4.y; acc[2][2] += a4.z*b4.z; acc[2][3] += a4.z*b4.w;
            acc[3][0] += a4.w*b4.x; acc[3][1] += a4.w*b4.y; acc[3][2] += a4.w*b4.z; acc[3][3] += a4.w*b4.w;
        }
        __syncthreads();
    }
    // ---- epilogue
    float bv[4] = {0.f, 0.f, 0.f, 0.f};
    if (bias) {
        bv[0] = bias[bn+tx*4+0]; bv[1] = bias[bn+tx*4+1];
        bv[2] = bias[bn+tx*4+2]; bv[3] = bias[bn+tx*4+3];
    }
    #pragma unroll
    for (int j = 0; j < 4; ++j) {
        int row = bm + ty * 4 + j;
        float4 o4;
        o4.x = acc[j][0] + bv[0]; o4.y = acc[j][1] + bv[1];
        o4.z = acc[j][2] + bv[2]; o4.w = acc[j][3] + bv[3];
        if (ACT) { o4.x = tanhf(o4.x); o4.y = tanhf(o4.y); o4.z = tanhf(o4.z); o4.w = tanhf(o4.w); }
        *(float4*)&C[(size_t)row * ldc + bn + tx * 4] = o4;
    }
}

// Trunk layer 2/3 GEMM: A[b, p] = (p<8192) ? h[b, p>>6] * z[b, p&63] : z[b, p-8192]
// B[p, n]  = (p<8192) ? W2[p&63, colbase + (p>>6)*128 + n] : W2[p-8192, biasbase + n]
// Writes split-K partials: Cpart[kz][2048][128].
__global__ __launch_bounds__(256)
void gemm_hz(const float* __restrict__ h,   // [2048,128]
             const float* __restrict__ z,   // [2048,64]
             const float* __restrict__ W2,  // [64, 33409]
             float* __restrict__ Cpart,
             int colbase, int biasbase)
{
    __shared__ float Ast[BK][BM];
    __shared__ float Bs[BK][BN];
    const int tid = threadIdx.x;
    const int tx = tid & 15, ty = tid >> 4;
    const int bm = blockIdx.y * BM, bn = blockIdx.x * BN;
    const int kz = blockIdx.z;
    const int ar = tid >> 2, aq = tid & 3;
    const int bk = tid >> 4, bq = tid & 15;
    float acc[4][4] = {};

    const int kend = (kz + 1) * KSLICE;
    for (int k0 = kz * KSLICE; k0 < kend; k0 += BK) {
        // ---- stage A
        {
            int b = bm + ar;
            int p0 = k0 + aq * 4;
            float4 av;
            if (p0 < 8192) {
                float hv = h[b * 128 + (p0 >> 6)];
                float4 z4 = *(const float4*)&z[b * 64 + (p0 & 63)];
                av = make_float4(hv * z4.x, hv * z4.y, hv * z4.z, hv * z4.w);
            } else {
                av = *(const float4*)&z[b * 64 + (p0 - 8192)];
            }
            Ast[aq*4+0][ar] = av.x; Ast[aq*4+1][ar] = av.y;
            Ast[aq*4+2][ar] = av.z; Ast[aq*4+3][ar] = av.w;
        }
        // ---- stage B (scalar: LDP odd -> misaligned for float4)
        {
            int p = k0 + bk;
            const float* wr;
            if (p < 8192) {
                wr = &W2[(size_t)(p & 63) * LDP + colbase + (size_t)(p >> 6) * 128];
            } else {
                wr = &W2[(size_t)(p - 8192) * LDP + biasbase];
            }
            int n0 = bn + bq * 4;
            Bs[bk][bq*4+0] = wr[n0+0]; Bs[bk][bq*4+1] = wr[n0+1];
            Bs[bk][bq*4+2] = wr[n0+2]; Bs[bk][bq*4+3] = wr[n0+3];
        }
        __syncthreads();
        #pragma unroll
        for (int kk = 0; kk < BK; ++kk) {
            float4 a4 = *(const float4*)&Ast[kk][ty * 4];
            float4 b4 = *(const float4*)&Bs[kk][tx * 4];
            acc[0][0] += a4.x*b4.x; acc[0][1] += a4.x*b4.y; acc[0][2] += a4.x*b4.z; acc[0][3] += a4.x*b4.w;
            acc[1][0] += a4.y*b4.x; acc[1][1] += a4.y*b4.y; acc[1][2] += a4.y*b4.z; acc[1][3] += a4.y*b4.w;
            acc[2][0] += a4.z*b4.x; acc[2][1] += a4.z*b4.y; acc[2][2] += a4.z*b4.z; acc[2][3] += a4.z*b4.w;
            acc[3][0] += a4.w*b4.x; acc[3][1] += a4.w*b4.y; acc[3][2] += a4.w*b4.z; acc[3][3] += a4.w*b4.w;
        }
        __syncthreads();
    }
    #pragma unroll
    for (int j = 0; j < 4; ++j) {
        int row = bm + ty * 4 + j;
        float4 o4 = make_float4(acc[j][0], acc[j][1], acc[j][2], acc[j][3]);
        *(float4*)&Cpart[((size_t)kz * 2048 + row) * 128 + bn + tx * 4] = o4;
    }
}

__global__ __launch_bounds__(256)
void reduce_tanh(const float* __restrict__ Cpart, float* __restrict__ hout)
{
    int idx = blockIdx.x * 256 + threadIdx.x;   // 2048*128 total
    const size_t S = (size_t)2048 * 128;
    float s = Cpart[idx] + Cpart[idx + S] + Cpart[idx + 2*S] + Cpart[idx + 3*S];
    hout[idx] = tanhf(s);
}

// h1[b,o] = tanh( t[b] * c1[b,128+o] + c1[b,o] )
__global__ __launch_bounds__(256)
void h1_kernel(const float* __restrict__ c1, const float* __restrict__ t,
               float* __restrict__ h1)
{
    int idx = blockIdx.x * 256 + threadIdx.x;   // 2048*128
    int b = idx >> 7, o = idx & 127;
    h1[idx] = tanhf(t[b] * c1[b * 256 + 128 + o] + c1[b * 256 + o]);
}

// q[b] = sum_k z[b,k] * ( W2[k,33280] + sum_i h3[b,i]*W2[k,33281+i] )
// out[b] = u[b,0] + t[b]*q[b].  One wave per sample, 4 samples/block.
__global__ __launch_bounds__(256)
void out_kernel(const float* __restrict__ h3, const float* __restrict__ z,
                const float* __restrict__ W2, const float* __restrict__ t,
                const float* __restrict__ u, float* __restrict__ out)
{
    __shared__ float sh[4][128];
    const int wv = threadIdx.x >> 6, l = threadIdx.x & 63;
    const int b = blockIdx.x * 4 + wv;
    sh[wv][l] = h3[b * 128 + l];
    sh[wv][64 + l] = h3[b * 128 + 64 + l];
    __syncthreads();
    const float* wrow = &W2[(size_t)l * LDP + 33280];
    float acc = wrow[0];
    #pragma unroll 8
    for (int i = 0; i < 128; ++i) acc += sh[wv][i] * wrow[1 + i];
    float p = z[b * 64 + l] * acc;
    #pragma unroll
    for (int off = 32; off > 0; off >>= 1) p += __shfl_down(p, off);
    if (l == 0) out[b] = u[b * 128] + t[b] * p;
}

extern "C" void kernel_launch(void* const* d_in, const int* in_sizes, int n_in,
                              void* d_out, int out_size, void* d_ws, size_t ws_size,
                              hipStream_t stream)
{
    const float* t   = (const float*)d_in[0];
    const float* u   = (const float*)d_in[1];
    const float* bw0 = (const float*)d_in[2];
    const float* bb0 = (const float*)d_in[3];
    const float* bw1 = (const float*)d_in[4];
    const float* bb1 = (const float*)d_in[5];
    const float* bw2 = (const float*)d_in[6];
    const float* bb2 = (const float*)d_in[7];
    const float* bw3 = (const float*)d_in[8];
    const float* bb3 = (const float*)d_in[9];
    const float* bw4 = (const float*)d_in[10];
    const float* bb4 = (const float*)d_in[11];
    const float* W1  = (const float*)d_in[12];
    const float* W2  = (const float*)d_in[13];
    float* out = (float*)d_out;

    float* ws   = (float*)d_ws;
    float* actA = ws;                          // 2048*1024
    float* actB = actA + (size_t)2048 * 1024;  // 2048*1024
    float* z    = actB + (size_t)2048 * 1024;  // 2048*64
    float* c1   = z    + (size_t)2048 * 64;    // 2048*256
    float* h1   = c1   + (size_t)2048 * 256;   // 2048*128
    float* h2   = h1   + (size_t)2048 * 128;   // 2048*128
    float* h3   = h2   + (size_t)2048 * 128;   // 2048*128
    float* Cp   = h3   + (size_t)2048 * 128;   // 4*2048*128
    // total = 6,684,672 floats = 26.7 MB

    dim3 blk(256);
    // ---- branch MLP
    gemm_f32<1><<<dim3(16, 32), blk, 0, stream>>>(u,    128,  bw0, 1024, 0, bb0, actA, 1024, 2048, 1024, 128);
    gemm_f32<1><<<dim3(16, 32), blk, 0, stream>>>(actA, 1024, bw1, 1024, 0, bb1, actB, 1024, 2048, 1024, 1024);
    gemm_f32<1><<<dim3(16, 32), blk, 0, stream>>>(actB, 1024, bw2, 1024, 0, bb2, actA, 1024, 2048, 1024, 1024);
    gemm_f32<1><<<dim3(16, 32), blk, 0, stream>>>(actA, 1024, bw3, 1024, 0, bb3, actB, 1024, 2048, 1024, 1024);
    gemm_f32<0><<<dim3(16, 32), blk, 0, stream>>>(actB, 1024, bw4, 1024, 0, bb4, actA, 1024, 2048, 1024, 1024);
    // ---- z = net @ W1   [2048,64]
    gemm_f32<0><<<dim3(1, 32),  blk, 0, stream>>>(actA, 1024, W1,  64,   0, nullptr, z, 64, 2048, 64, 1024);
    // ---- trunk layer 1: c1 = z @ W2[:,0:256], then h1 elementwise
    gemm_f32<0><<<dim3(4, 32),  blk, 0, stream>>>(z,    64,   W2,  LDP,  0, nullptr, c1, 256, 2048, 256, 64);
    h1_kernel<<<1024, blk, 0, stream>>>(c1, t, h1);
    // ---- trunk layer 2
    gemm_hz<<<dim3(2, 32, SPLITK), blk, 0, stream>>>(h1, z, W2, Cp, 384, 256);
    reduce_tanh<<<1024, blk, 0, stream>>>(Cp, h2);
    // ---- trunk layer 3
    gemm_hz<<<dim3(2, 32, SPLITK), blk, 0, stream>>>(h2, z, W2, Cp, 16896, 16768);
    reduce_tanh<<<1024, blk, 0, stream>>>(Cp, h3);
    // ---- trunk layer 4 + final combine
    out_kernel<<<512, blk, 0, stream>>>(h3, z, W2, t, u, out);
}

// Round 4
// 320.102 us; speedup vs baseline: 2.3407x; 2.3407x over previous
//
#include <hip/hip_runtime.h>
#include <hip/hip_bf16.h>
#include <stdint.h>

typedef unsigned short u16;
typedef unsigned int   u32;
typedef short s16x8 __attribute__((ext_vector_type(8)));
typedef float f32x4 __attribute__((ext_vector_type(4)));

#define LDP 33409

__device__ __forceinline__ u16 f2bf(float f) {
    union { float f; u32 u; } v; v.f = f;
    u32 r = v.u + 0x7fffu + ((v.u >> 16) & 1u);
    return (u16)(r >> 16);
}
__device__ __forceinline__ float bf2f(u16 h) {
    union { u32 u; float f; } v; v.u = ((u32)h) << 16;
    return v.f;
}
__device__ __forceinline__ float fast_tanh(float x) {
    float e = __expf(2.0f * x);
    return 1.0f - 2.0f / (e + 1.0f);
}
__device__ __forceinline__ f32x4 MFMA(s16x8 a, s16x8 b, f32x4 c) {
    return __builtin_amdgcn_mfma_f32_16x16x32_bf16(a, b, c, 0, 0, 0);
}
__device__ __forceinline__ void gload_lds16(const void* g, void* l) {
    __builtin_amdgcn_global_load_lds(
        (const __attribute__((address_space(1))) u32*)(uintptr_t)g,
        (__attribute__((address_space(3))) u32*)(uintptr_t)l, 16, 0, 0);
}

// ---------------------------------------------------------------------------
// prep kernels — all emit (hi, lo) bf16 pairs: lo at element offset dLo
// ---------------------------------------------------------------------------

__global__ __launch_bounds__(256)
void cvt_pair(const float* __restrict__ s, u16* __restrict__ d, int dLo, int n) {
    int i = (blockIdx.x * 256 + threadIdx.x) * 4;
    if (i >= n) return;
    float4 a = *(const float4*)&s[i];
    u16 h0 = f2bf(a.x), h1 = f2bf(a.y), h2 = f2bf(a.z), h3 = f2bf(a.w);
    uint2 hi, lo;
    hi.x = (u32)h0 | ((u32)h1 << 16);
    hi.y = (u32)h2 | ((u32)h3 << 16);
    lo.x = (u32)f2bf(a.x - bf2f(h0)) | ((u32)f2bf(a.y - bf2f(h1)) << 16);
    lo.y = (u32)f2bf(a.z - bf2f(h2)) | ((u32)f2bf(a.w - bf2f(h3)) << 16);
    *(uint2*)&d[i] = hi;
    *(uint2*)&d[dLo + i] = lo;
}

// dst[c][r] pair = src[r][c] (f32); 64x64 tiles
__global__ __launch_bounds__(256)
void transpose_cvt(const float* __restrict__ src, int ldsrc,
                   u16* __restrict__ dst, int lddst, int dLo) {
    __shared__ float tile[64][65];
    const int rb = blockIdx.y * 64, cb = blockIdx.x * 64;
    for (int i = threadIdx.x; i < 64 * 64; i += 256) {
        int r = i >> 6, c = i & 63;
        tile[r][c] = src[(size_t)(rb + r) * ldsrc + cb + c];
    }
    __syncthreads();
    for (int i = threadIdx.x; i < 64 * 64; i += 256) {
        int c = i >> 6, r = i & 63;
        float v = tile[r][c];
        u16 hi = f2bf(v);
        size_t o = (size_t)(cb + c) * lddst + rb + r;
        dst[o] = hi;
        dst[dLo + o] = f2bf(v - bf2f(hi));
    }
}

// gathered trunk weight view pair: Bt[n][p], n<128, p<8256, lo at +128*8256
__global__ __launch_bounds__(256)
void gather_trunk(const float* __restrict__ W2, u16* __restrict__ Bt,
                  int colbase, int biasbase) {
    __shared__ float tile[64][130];
    const int pb = blockIdx.x * 64;
    for (int i = threadIdx.x; i < 64 * 128; i += 256) {
        int p = pb + (i >> 7), n = i & 127;
        float v = (p < 8192)
            ? W2[(size_t)(p & 63) * LDP + colbase + (size_t)(p >> 6) * 128 + n]
            : W2[(size_t)(p - 8192) * LDP + biasbase + n];
        tile[i >> 7][n] = v;
    }
    __syncthreads();
    const int BLO = 128 * 8256;
    for (int i = threadIdx.x; i < 64 * 128; i += 256) {
        int n = i >> 6, dp = i & 63;
        float v = tile[dp][n];
        u16 hi = f2bf(v);
        size_t o = (size_t)n * 8256 + pb + dp;
        Bt[o] = hi;
        Bt[BLO + o] = f2bf(v - bf2f(hi));
    }
}

// exact-f32: BWt[n][k] pair = (bw4 @ W1)[k][n]
__global__ __launch_bounds__(256)
void bw_kernel(const float* __restrict__ bw4, const float* __restrict__ W1,
               u16* __restrict__ BWt) {
    const int n = threadIdx.x & 63;
    const int k = blockIdx.x * 4 + (threadIdx.x >> 6);
    float a = 0.f;
    for (int j = 0; j < 1024; ++j) a = fmaf(bw4[(size_t)k * 1024 + j], W1[j * 64 + n], a);
    u16 hi = f2bf(a);
    BWt[(size_t)n * 1024 + k] = hi;
    BWt[64 * 1024 + (size_t)n * 1024 + k] = f2bf(a - bf2f(hi));
}

__global__ __launch_bounds__(64)
void bz_kernel(const float* __restrict__ bb4, const float* __restrict__ W1,
               float* __restrict__ bz) {
    int n = threadIdx.x;
    float a = 0.f;
    for (int j = 0; j < 1024; ++j) a = fmaf(bb4[j], W1[j * 64 + n], a);
    bz[n] = a;
}

// ---------------------------------------------------------------------------
// split-precision MFMA GEMM: C = act(A @ Bt^T + bias), A/Bt are (hi,lo) pairs.
// 3-term: ah*bh + ah*bl + al*bh  ->  ~f32 accuracy.
// OUT: 0=f32  1=bf16 pair  3=f32 split-K partial
// ---------------------------------------------------------------------------
template<int BN, int ACT, int OUT>
__global__ __launch_bounds__(256, 1)
void mfma_gemm(const u16* __restrict__ A, int aLo, int lda,
               const u16* __restrict__ Bt, int bLo, int ldb,
               const float* __restrict__ bias,
               void* __restrict__ Cout, int cLo, int ldc,
               int M, int K, int SK)
{
    constexpr int NFN = BN / 32;
    constexpr int NBR = BN / 64;
    __shared__ __align__(16) u16 As[2][2][64 * 32];
    __shared__ __align__(16) u16 Bs[2][2][BN * 32];
    const int tid = threadIdx.x, lane = tid & 63, wid = tid >> 6;
    const int wr = wid >> 1, wc = wid & 1;
    const int bn = blockIdx.x * BN, bm = blockIdx.y * 64;
    const int kz = blockIdx.z;
    const int NT = K >> 5;
    const int t0 = (NT * kz) / SK, t1 = (NT * (kz + 1)) / SK;
    const int arow = tid >> 2, achk = tid & 3;
    const u16* aSrc = A + (size_t)(bm + arow) * lda + (achk ^ (arow & 3)) * 8;

    f32x4 acc[2][NFN] = {};

    auto STAGE = [&](int buf, int t) {
        const int k0 = t << 5;
        gload_lds16(aSrc + k0,       (char*)&As[buf][0][0] + wid * 1024);
        gload_lds16(aSrc + aLo + k0, (char*)&As[buf][1][0] + wid * 1024);
        #pragma unroll
        for (int r = 0; r < NBR; ++r) {
            int n = (r * 256 + tid) >> 2;
            // NOTE: global row is (bn + n); bn is a multiple of 64 so the
            // (n & 3) LDS swizzle term is unchanged.  [r3 bug: bn was missing]
            const u16* bsrc = Bt + (size_t)(bn + n) * ldb + k0 + (achk ^ (n & 3)) * 8;
            gload_lds16(bsrc,       (char*)&Bs[buf][0][0] + r * 4096 + wid * 1024);
            gload_lds16(bsrc + bLo, (char*)&Bs[buf][1][0] + r * 4096 + wid * 1024);
        }
    };
    auto COMPUTE = [&](int buf) {
        s16x8 ah[2], al[2];
        #pragma unroll
        for (int mi = 0; mi < 2; ++mi) {
            int row = wr * 32 + mi * 16 + (lane & 15);
            int s = (lane >> 4) ^ (row & 3);
            ah[mi] = *(const s16x8*)&As[buf][0][row * 32 + s * 8];
            al[mi] = *(const s16x8*)&As[buf][1][row * 32 + s * 8];
        }
        #pragma unroll
        for (int ni = 0; ni < NFN; ++ni) {
            int n = wc * (BN / 2) + ni * 16 + (lane & 15);
            int s = (lane >> 4) ^ (n & 3);
            s16x8 bh = *(const s16x8*)&Bs[buf][0][n * 32 + s * 8];
            s16x8 bl = *(const s16x8*)&Bs[buf][1][n * 32 + s * 8];
            #pragma unroll
            for (int mi = 0; mi < 2; ++mi) {
                acc[mi][ni] = MFMA(ah[mi], bh, acc[mi][ni]);
                acc[mi][ni] = MFMA(ah[mi], bl, acc[mi][ni]);
                acc[mi][ni] = MFMA(al[mi], bh, acc[mi][ni]);
            }
        }
    };

    STAGE(0, t0);
    __syncthreads();
    const int nt = t1 - t0;
    for (int t = 0; t < nt; ++t) {
        if (t + 1 < nt) STAGE((t + 1) & 1, t0 + t + 1);
        COMPUTE(t & 1);
        __syncthreads();
    }

    #pragma unroll
    for (int mi = 0; mi < 2; ++mi)
    #pragma unroll
    for (int ni = 0; ni < NFN; ++ni) {
        const int col = bn + wc * (BN / 2) + ni * 16 + (lane & 15);
        const float bv = (OUT != 3 && bias) ? bias[col] : 0.f;
        #pragma unroll
        for (int j = 0; j < 4; ++j) {
            const int row = bm + wr * 32 + mi * 16 + (lane >> 4) * 4 + j;
            float v = acc[mi][ni][j] + bv;
            if (ACT) v = fast_tanh(v);
            if (OUT == 0)      ((float*)Cout)[(size_t)row * ldc + col] = v;
            else if (OUT == 1) {
                u16* C = (u16*)Cout;
                u16 hi = f2bf(v);
                size_t o = (size_t)row * ldc + col;
                C[o] = hi;
                C[cLo + o] = f2bf(v - bf2f(hi));
            } else {
                ((float*)Cout)[((size_t)kz * M + row) * ldc + col] = v;
            }
        }
    }
}

// ---------------------------------------------------------------------------
// Trunk GEMM, split-precision. A generated on the fly from h,z pairs:
//   p<8192: h[b,p>>6]*z[b,p&63] ; else z[b,p-8192].  K=8256, split-K=8.
// (B here has exactly 128 rows = full N; no bn offset exists.)
// ---------------------------------------------------------------------------
__global__ __launch_bounds__(256, 1)
void trunk_mfma(const u16* __restrict__ h, const u16* __restrict__ z,
                const u16* __restrict__ Bt, float* __restrict__ Cp)
{
    constexpr int NT = 258, SKT = 8;
    constexpr int HLO = 2048 * 128, ZLO = 2048 * 64, BLO = 128 * 8256;
    __shared__ __align__(16) u16 As[2][2][64 * 32];
    __shared__ __align__(16) u16 Bs[2][2][128 * 32];
    const int tid = threadIdx.x, lane = tid & 63, wid = tid >> 6;
    const int wr = wid >> 1, wc = wid & 1;
    const int bm = blockIdx.x * 64;
    const int kz = blockIdx.y;
    const int t0 = (NT * kz) / SKT, t1 = (NT * (kz + 1)) / SKT;
    const int arow = tid >> 2, achk = tid & 3;
    const int b = bm + arow;

    f32x4 acc[2][4] = {};

    auto STAGE = [&](int buf, int t) {
        const int p0 = t << 5;
        #pragma unroll
        for (int r = 0; r < 2; ++r) {
            int n = (r * 256 + tid) >> 2;
            const u16* bsrc = Bt + (size_t)n * 8256 + p0 + (achk ^ (n & 3)) * 8;
            gload_lds16(bsrc,       (char*)&Bs[buf][0][0] + r * 4096 + wid * 1024);
            gload_lds16(bsrc + BLO, (char*)&Bs[buf][1][0] + r * 4096 + wid * 1024);
        }
        const int pp = p0 + achk * 8;
        u16 hi8[8], lo8[8];
        if (pp < 8192) {
            const int hidx = b * 128 + (pp >> 6);
            const float hf = bf2f(h[hidx]) + bf2f(h[HLO + hidx]);
            s16x8 zh = *(const s16x8*)&z[b * 64 + (pp & 63)];
            s16x8 zl = *(const s16x8*)&z[ZLO + b * 64 + (pp & 63)];
            #pragma unroll
            for (int j = 0; j < 8; ++j) {
                float pf = hf * (bf2f((u16)zh[j]) + bf2f((u16)zl[j]));
                hi8[j] = f2bf(pf);
                lo8[j] = f2bf(pf - bf2f(hi8[j]));
            }
        } else {
            s16x8 zh = *(const s16x8*)&z[b * 64 + (pp - 8192)];
            s16x8 zl = *(const s16x8*)&z[ZLO + b * 64 + (pp - 8192)];
            #pragma unroll
            for (int j = 0; j < 8; ++j) { hi8[j] = (u16)zh[j]; lo8[j] = (u16)zl[j]; }
        }
        const int s = achk ^ (arow & 3);
        *(s16x8*)&As[buf][0][arow * 32 + s * 8] = *(s16x8*)hi8;
        *(s16x8*)&As[buf][1][arow * 32 + s * 8] = *(s16x8*)lo8;
    };
    auto COMPUTE = [&](int buf) {
        s16x8 ah[2], al[2];
        #pragma unroll
        for (int mi = 0; mi < 2; ++mi) {
            int row = wr * 32 + mi * 16 + (lane & 15);
            int s = (lane >> 4) ^ (row & 3);
            ah[mi] = *(const s16x8*)&As[buf][0][row * 32 + s * 8];
            al[mi] = *(const s16x8*)&As[buf][1][row * 32 + s * 8];
        }
        #pragma unroll
        for (int ni = 0; ni < 4; ++ni) {
            int n = wc * 64 + ni * 16 + (lane & 15);
            int s = (lane >> 4) ^ (n & 3);
            s16x8 bh = *(const s16x8*)&Bs[buf][0][n * 32 + s * 8];
            s16x8 bl = *(const s16x8*)&Bs[buf][1][n * 32 + s * 8];
            #pragma unroll
            for (int mi = 0; mi < 2; ++mi) {
                acc[mi][ni] = MFMA(ah[mi], bh, acc[mi][ni]);
                acc[mi][ni] = MFMA(ah[mi], bl, acc[mi][ni]);
                acc[mi][ni] = MFMA(al[mi], bh, acc[mi][ni]);
            }
        }
    };

    STAGE(0, t0);
    __syncthreads();
    const int nt = t1 - t0;
    for (int t = 0; t < nt; ++t) {
        if (t + 1 < nt) STAGE((t + 1) & 1, t0 + t + 1);
        COMPUTE(t & 1);
        __syncthreads();
    }

    #pragma unroll
    for (int mi = 0; mi < 2; ++mi)
    #pragma unroll
    for (int ni = 0; ni < 4; ++ni) {
        const int col = wc * 64 + ni * 16 + (lane & 15);
        #pragma unroll
        for (int j = 0; j < 4; ++j) {
            const int row = bm + wr * 32 + mi * 16 + (lane >> 4) * 4 + j;
            Cp[((size_t)kz * 2048 + row) * 128 + col] = acc[mi][ni][j];
        }
    }
}

// ---------------------------------------------------------------------------
// small fused kernels
// ---------------------------------------------------------------------------
__global__ __launch_bounds__(256)
void reduce_tanh_pair(const float* __restrict__ Cp, u16* __restrict__ hout) {
    const int idx = blockIdx.x * 256 + threadIdx.x;      // 2048*128
    const size_t S = (size_t)2048 * 128;
    float s = 0.f;
    #pragma unroll
    for (int k = 0; k < 8; ++k) s += Cp[idx + k * S];
    float v = fast_tanh(s);
    u16 hi = f2bf(v);
    hout[idx] = hi;
    hout[2048 * 128 + idx] = f2bf(v - bf2f(hi));
}

__global__ __launch_bounds__(256)
void reduce_z(const float* __restrict__ zp, const float* __restrict__ bz,
              u16* __restrict__ zpair) {
    const int idx = blockIdx.x * 256 + threadIdx.x;      // 2048*64
    const size_t S = (size_t)2048 * 64;
    float s = bz[idx & 63];
    #pragma unroll
    for (int k = 0; k < 4; ++k) s += zp[idx + k * S];
    u16 hi = f2bf(s);
    zpair[idx] = hi;
    zpair[2048 * 64 + idx] = f2bf(s - bf2f(hi));
}

__global__ __launch_bounds__(256)
void h1_kernel(const float* __restrict__ c1, const float* __restrict__ t,
               u16* __restrict__ h1) {
    const int idx = blockIdx.x * 256 + threadIdx.x;      // 2048*128
    const int b = idx >> 7, o = idx & 127;
    float v = fast_tanh(t[b] * c1[b * 256 + 128 + o] + c1[b * 256 + o]);
    u16 hi = f2bf(v);
    h1[idx] = hi;
    h1[2048 * 128 + idx] = f2bf(v - bf2f(hi));
}

__global__ __launch_bounds__(256)
void out_kernel(const u16* __restrict__ h3, const u16* __restrict__ z,
                const float* __restrict__ W2, const float* __restrict__ t,
                const float* __restrict__ u, float* __restrict__ out) {
    __shared__ float sh[4][128];
    const int wv = threadIdx.x >> 6, l = threadIdx.x & 63;
    const int b = blockIdx.x * 4 + wv;
    const int HLO = 2048 * 128, ZLO = 2048 * 64;
    sh[wv][l]      = bf2f(h3[b * 128 + l])      + bf2f(h3[HLO + b * 128 + l]);
    sh[wv][64 + l] = bf2f(h3[b * 128 + 64 + l]) + bf2f(h3[HLO + b * 128 + 64 + l]);
    __syncthreads();
    const float* wrow = &W2[(size_t)l * LDP + 33280];
    float acc = wrow[0];
    #pragma unroll 8
    for (int i = 0; i < 128; ++i) acc = fmaf(sh[wv][i], wrow[1 + i], acc);
    float p = (bf2f(z[b * 64 + l]) + bf2f(z[ZLO + b * 64 + l])) * acc;
    #pragma unroll
    for (int off = 32; off > 0; off >>= 1) p += __shfl_down(p, off);
    if (l == 0) out[b] = u[b * 128] + t[b] * p;
}

// ---------------------------------------------------------------------------
extern "C" void kernel_launch(void* const* d_in, const int* in_sizes, int n_in,
                              void* d_out, int out_size, void* d_ws, size_t ws_size,
                              hipStream_t stream)
{
    const float* t   = (const float*)d_in[0];
    const float* u   = (const float*)d_in[1];
    const float* bw0 = (const float*)d_in[2];
    const float* bb0 = (const float*)d_in[3];
    const float* bw1 = (const float*)d_in[4];
    const float* bb1 = (const float*)d_in[5];
    const float* bw2 = (const float*)d_in[6];
    const float* bb2 = (const float*)d_in[7];
    const float* bw3 = (const float*)d_in[8];
    const float* bb3 = (const float*)d_in[9];
    const float* bw4 = (const float*)d_in[10];
    const float* bb4 = (const float*)d_in[11];
    const float* W1  = (const float*)d_in[12];
    const float* W2  = (const float*)d_in[13];
    float* out = (float*)d_out;

    // ---- workspace layout (explicit offsets, bytes). Pairs: lo at +size/2.
    char* base = (char*)d_ws;
    u16*   ubf  = (u16*)(base);                          // 1,048,576
    u16*   bw0t = (u16*)(base + 1048576);                //   524,288
    u16*   bw1t = (u16*)(base + 1572864);                // 4,194,304
    u16*   bw2t = (u16*)(base + 5767168);                // 4,194,304
    u16*   bw3t = (u16*)(base + 9961472);                // 4,194,304 (ends 14,155,776)
    u16*   Wc1t = (u16*)(base + 14155776);               //    65,536
    u16*   BWt  = (u16*)(base + 14221312);               //   262,144
    float* bz   = (float*)(base + 14483456);             //       256
    u16*   z    = (u16*)(base + 14483712);               //   524,288
    u16*   h1   = (u16*)(base + 15008000);               // 1,048,576
    u16*   h2   = (u16*)(base + 16056576);               // 1,048,576
    u16*   h3   = (u16*)(base + 17105152);               // 1,048,576
    u16*   actA = (u16*)(base + 18153728);               // 8,388,608
    u16*   actB = (u16*)(base + 26542336);               // 8,388,608 (ends 34,930,944)
    // overlays (stream-ordered liveness):
    float* zc = (float*)(base + 1572864);                // 2 MB over bw1t (dead after L1)
    float* c1 = (float*)(base + 5767168);                // 2 MB over bw2t (dead after L2)
    u16*   Bt = (u16*)(base + 7864320);                  // 4.22 MB over bw2t[2MB:]+bw3t (dead after L3)
    float* Cp = (float*)(base + 18153728);               // 8 MB over actA (dead after L3)

    constexpr int ALO = 2048 * 1024;   // act pair lo offset (elements)
    dim3 blk(256);

    // ---- prep
    cvt_pair<<<256, blk, 0, stream>>>(u, ubf, 2048 * 128, 2048 * 128);
    transpose_cvt<<<dim3(16, 2),  blk, 0, stream>>>(bw0, 1024, bw0t, 128,  1024 * 128);
    transpose_cvt<<<dim3(16, 16), blk, 0, stream>>>(bw1, 1024, bw1t, 1024, 1024 * 1024);
    transpose_cvt<<<dim3(16, 16), blk, 0, stream>>>(bw2, 1024, bw2t, 1024, 1024 * 1024);
    transpose_cvt<<<dim3(16, 16), blk, 0, stream>>>(bw3, 1024, bw3t, 1024, 1024 * 1024);
    transpose_cvt<<<dim3(4, 1),   blk, 0, stream>>>(W2, LDP, Wc1t, 64, 256 * 64);
    bw_kernel<<<256, blk, 0, stream>>>(bw4, W1, BWt);
    bz_kernel<<<1, 64, 0, stream>>>(bb4, W1, bz);

    // ---- branch MLP (bw4@W1 folded into BWt)
    mfma_gemm<128, 1, 1><<<dim3(8, 32, 1), blk, 0, stream>>>(
        ubf, 2048 * 128, 128, bw0t, 1024 * 128, 128, bb0, actA, ALO, 1024, 2048, 128, 1);
    mfma_gemm<128, 1, 1><<<dim3(8, 32, 1), blk, 0, stream>>>(
        actA, ALO, 1024, bw1t, 1024 * 1024, 1024, bb1, actB, ALO, 1024, 2048, 1024, 1);
    mfma_gemm<128, 1, 1><<<dim3(8, 32, 1), blk, 0, stream>>>(
        actB, ALO, 1024, bw2t, 1024 * 1024, 1024, bb2, actA, ALO, 1024, 2048, 1024, 1);
    mfma_gemm<128, 1, 1><<<dim3(8, 32, 1), blk, 0, stream>>>(
        actA, ALO, 1024, bw3t, 1024 * 1024, 1024, bb3, actB, ALO, 1024, 2048, 1024, 1);
    // ---- z = actB @ BW (+bz), split-K=4 (partials into zc over bw1t)
    mfma_gemm<64, 0, 3><<<dim3(1, 32, 4), blk, 0, stream>>>(
        actB, ALO, 1024, BWt, 64 * 1024, 1024, nullptr, zc, 0, 64, 2048, 1024, 4);
    reduce_z<<<512, blk, 0, stream>>>(zc, bz, z);
    // ---- trunk layer 1: c1 = z @ W2[:,0:256] (f32), then h1 pair
    mfma_gemm<128, 0, 0><<<dim3(2, 32, 1), blk, 0, stream>>>(
        z, 2048 * 64, 64, Wc1t, 256 * 64, 64, nullptr, c1, 0, 256, 2048, 64, 1);
    h1_kernel<<<1024, blk, 0, stream>>>(c1, t, h1);
    // ---- trunk layer 2 (gather just-in-time into shared Bt buffer)
    gather_trunk<<<129, blk, 0, stream>>>(W2, Bt, 384, 256);
    trunk_mfma<<<dim3(32, 8), blk, 0, stream>>>(h1, z, Bt, Cp);
    reduce_tanh_pair<<<1024, blk, 0, stream>>>(Cp, h2);
    // ---- trunk layer 3
    gather_trunk<<<129, blk, 0, stream>>>(W2, Bt, 16896, 16768);
    trunk_mfma<<<dim3(32, 8), blk, 0, stream>>>(h2, z, Bt, Cp);
    reduce_tanh_pair<<<1024, blk, 0, stream>>>(Cp, h3);
    // ---- trunk layer 4 + combine
    out_kernel<<<512, blk, 0, stream>>>(h3, z, W2, t, u, out);
}

// Round 5
// 249.769 us; speedup vs baseline: 2.9998x; 1.2816x over previous
//
#include <hip/hip_runtime.h>
#include <hip/hip_bf16.h>
#include <stdint.h>

typedef unsigned short u16;
typedef unsigned int   u32;
typedef short s16x8 __attribute__((ext_vector_type(8)));
typedef float f32x4 __attribute__((ext_vector_type(4)));

#define LDP 33409

__device__ __forceinline__ u16 f2bf(float f) {
    union { float f; u32 u; } v; v.f = f;
    u32 r = v.u + 0x7fffu + ((v.u >> 16) & 1u);
    return (u16)(r >> 16);
}
__device__ __forceinline__ float bf2f(u16 h) {
    union { u32 u; float f; } v; v.u = ((u32)h) << 16;
    return v.f;
}
__device__ __forceinline__ float fast_tanh(float x) {
    float e = __expf(2.0f * x);
    return 1.0f - 2.0f / (e + 1.0f);
}
__device__ __forceinline__ f32x4 MFMA(s16x8 a, s16x8 b, f32x4 c) {
    return __builtin_amdgcn_mfma_f32_16x16x32_bf16(a, b, c, 0, 0, 0);
}
__device__ __forceinline__ void gload_lds16(const void* g, void* l) {
    __builtin_amdgcn_global_load_lds(
        (const __attribute__((address_space(1))) u32*)(uintptr_t)g,
        (__attribute__((address_space(3))) u32*)(uintptr_t)l, 16, 0, 0);
}

// ---------------------------------------------------------------------------
// prep kernels.  Weights -> (hi,lo) bf16 pairs; activations plain bf16.
// ---------------------------------------------------------------------------

__global__ __launch_bounds__(256)
void cvt_plain(const float* __restrict__ s, u16* __restrict__ d, int n) {
    int i = (blockIdx.x * 256 + threadIdx.x) * 8;
    if (i >= n) return;
    float4 a = *(const float4*)&s[i];
    float4 b = *(const float4*)&s[i + 4];
    uint4 o;
    o.x = (u32)f2bf(a.x) | ((u32)f2bf(a.y) << 16);
    o.y = (u32)f2bf(a.z) | ((u32)f2bf(a.w) << 16);
    o.z = (u32)f2bf(b.x) | ((u32)f2bf(b.y) << 16);
    o.w = (u32)f2bf(b.z) | ((u32)f2bf(b.w) << 16);
    *(uint4*)&d[i] = o;
}

// dst[c][r] pair = src[r][c] (f32); 64x64 tiles
__global__ __launch_bounds__(256)
void transpose_cvt(const float* __restrict__ src, int ldsrc,
                   u16* __restrict__ dst, int lddst, int dLo) {
    __shared__ float tile[64][65];
    const int rb = blockIdx.y * 64, cb = blockIdx.x * 64;
    for (int i = threadIdx.x; i < 64 * 64; i += 256) {
        int r = i >> 6, c = i & 63;
        tile[r][c] = src[(size_t)(rb + r) * ldsrc + cb + c];
    }
    __syncthreads();
    for (int i = threadIdx.x; i < 64 * 64; i += 256) {
        int c = i >> 6, r = i & 63;
        float v = tile[r][c];
        u16 hi = f2bf(v);
        size_t o = (size_t)(cb + c) * lddst + rb + r;
        dst[o] = hi;
        dst[dLo + o] = f2bf(v - bf2f(hi));
    }
}

// gathered trunk weight view pair: Bt[n][p], n<128, p<8256, lo at +128*8256
__global__ __launch_bounds__(256)
void gather_trunk(const float* __restrict__ W2, u16* __restrict__ Bt,
                  int colbase, int biasbase) {
    __shared__ float tile[64][130];
    const int pb = blockIdx.x * 64;
    for (int i = threadIdx.x; i < 64 * 128; i += 256) {
        int p = pb + (i >> 7), n = i & 127;
        float v = (p < 8192)
            ? W2[(size_t)(p & 63) * LDP + colbase + (size_t)(p >> 6) * 128 + n]
            : W2[(size_t)(p - 8192) * LDP + biasbase + n];
        tile[i >> 7][n] = v;
    }
    __syncthreads();
    const int BLO = 128 * 8256;
    for (int i = threadIdx.x; i < 64 * 128; i += 256) {
        int n = i >> 6, dp = i & 63;
        float v = tile[dp][n];
        u16 hi = f2bf(v);
        size_t o = (size_t)n * 8256 + pb + dp;
        Bt[o] = hi;
        Bt[BLO + o] = f2bf(v - bf2f(hi));
    }
}

// exact-f32: BWt[n][k] pair = (bw4 @ W1)[k][n]
__global__ __launch_bounds__(256)
void bw_kernel(const float* __restrict__ bw4, const float* __restrict__ W1,
               u16* __restrict__ BWt) {
    const int n = threadIdx.x & 63;
    const int k = blockIdx.x * 4 + (threadIdx.x >> 6);
    float a = 0.f;
    for (int j = 0; j < 1024; ++j) a = fmaf(bw4[(size_t)k * 1024 + j], W1[j * 64 + n], a);
    u16 hi = f2bf(a);
    BWt[(size_t)n * 1024 + k] = hi;
    BWt[64 * 1024 + (size_t)n * 1024 + k] = f2bf(a - bf2f(hi));
}

__global__ __launch_bounds__(64)
void bz_kernel(const float* __restrict__ bb4, const float* __restrict__ W1,
               float* __restrict__ bz) {
    int n = threadIdx.x;
    float a = 0.f;
    for (int j = 0; j < 1024; ++j) a = fmaf(bb4[j], W1[j * 64 + n], a);
    bz[n] = a;
}

// ---------------------------------------------------------------------------
// 2-term split GEMM: C = act(A @ Bt^T + bias); A plain bf16, Bt (hi,lo) pair.
// acc += ah*bh + ah*bl.  64x64 tile, 4 waves, dbuf LDS, 2 blocks/CU.
// OUT: 0=f32  1=bf16 plain  3=f32 split-K partial
// ---------------------------------------------------------------------------
template<int ACT, int OUT>
__global__ __launch_bounds__(256, 2)
void mfma_gemm(const u16* __restrict__ A, int lda,
               const u16* __restrict__ Bt, int bLo, int ldb,
               const float* __restrict__ bias,
               void* __restrict__ Cout, int ldc,
               int M, int K, int SK)
{
    __shared__ __align__(16) u16 As[2][64 * 32];        // 8 KB
    __shared__ __align__(16) u16 Bs[2][2][64 * 32];     // 16 KB
    const int tid = threadIdx.x, lane = tid & 63, wid = tid >> 6;
    const int wr = wid >> 1, wc = wid & 1;
    const int bn = blockIdx.x * 64, bm = blockIdx.y * 64;
    const int kz = blockIdx.z;
    const int NT = K >> 5;
    const int t0 = (NT * kz) / SK, t1 = (NT * (kz + 1)) / SK;
    const int arow = tid >> 2, achk = tid & 3;
    const u16* aSrc = A + (size_t)(bm + arow) * lda + (achk ^ (arow & 3)) * 8;
    const int brow = arow;   // B staging row (local), same decomposition
    const u16* bSrc = Bt + (size_t)(bn + brow) * ldb + (achk ^ (brow & 3)) * 8;

    f32x4 acc[2][2] = {};

    auto STAGE = [&](int buf, int t) {
        const int k0 = t << 5;
        gload_lds16(aSrc + k0,       (char*)&As[buf][0]    + wid * 1024);
        gload_lds16(bSrc + k0,       (char*)&Bs[buf][0][0] + wid * 1024);
        gload_lds16(bSrc + bLo + k0, (char*)&Bs[buf][1][0] + wid * 1024);
    };
    auto COMPUTE = [&](int buf) {
        s16x8 a[2];
        #pragma unroll
        for (int mi = 0; mi < 2; ++mi) {
            int row = wr * 32 + mi * 16 + (lane & 15);
            int s = (lane >> 4) ^ (row & 3);
            a[mi] = *(const s16x8*)&As[buf][row * 32 + s * 8];
        }
        #pragma unroll
        for (int ni = 0; ni < 2; ++ni) {
            int n = wc * 32 + ni * 16 + (lane & 15);
            int s = (lane >> 4) ^ (n & 3);
            s16x8 bh = *(const s16x8*)&Bs[buf][0][n * 32 + s * 8];
            s16x8 bl = *(const s16x8*)&Bs[buf][1][n * 32 + s * 8];
            #pragma unroll
            for (int mi = 0; mi < 2; ++mi) {
                acc[mi][ni] = MFMA(a[mi], bh, acc[mi][ni]);
                acc[mi][ni] = MFMA(a[mi], bl, acc[mi][ni]);
            }
        }
    };

    STAGE(0, t0);
    __syncthreads();
    const int nt = t1 - t0;
    for (int t = 0; t < nt; ++t) {
        if (t + 1 < nt) STAGE((t + 1) & 1, t0 + t + 1);
        COMPUTE(t & 1);
        __syncthreads();
    }

    #pragma unroll
    for (int mi = 0; mi < 2; ++mi)
    #pragma unroll
    for (int ni = 0; ni < 2; ++ni) {
        const int col = bn + wc * 32 + ni * 16 + (lane & 15);
        const float bv = (OUT != 3 && bias) ? bias[col] : 0.f;
        #pragma unroll
        for (int j = 0; j < 4; ++j) {
            const int row = bm + wr * 32 + mi * 16 + (lane >> 4) * 4 + j;
            float v = acc[mi][ni][j] + bv;
            if (ACT) v = fast_tanh(v);
            if (OUT == 0)      ((float*)Cout)[(size_t)row * ldc + col] = v;
            else if (OUT == 1) ((u16*)Cout)[(size_t)row * ldc + col] = f2bf(v);
            else ((float*)Cout)[((size_t)kz * M + row) * ldc + col] = v;
        }
    }
}

// ---------------------------------------------------------------------------
// Trunk GEMM, 2-term split. A (plain bf16) generated on the fly from h,z:
//   p<8192: h[b,p>>6]*z[b,p&63] ; else z[b,p-8192].  K=8256, split-K=16.
// ---------------------------------------------------------------------------
__global__ __launch_bounds__(256, 2)
void trunk_mfma(const u16* __restrict__ h, const u16* __restrict__ z,
                const u16* __restrict__ Bt, float* __restrict__ Cp)
{
    constexpr int NT = 258, SKT = 16;
    constexpr int BLO = 128 * 8256;
    __shared__ __align__(16) u16 As[2][64 * 32];         // 8 KB
    __shared__ __align__(16) u16 Bs[2][2][128 * 32];     // 32 KB
    const int tid = threadIdx.x, lane = tid & 63, wid = tid >> 6;
    const int wr = wid >> 1, wc = wid & 1;
    const int bm = blockIdx.x * 64;
    const int kz = blockIdx.y;
    const int t0 = (NT * kz) / SKT, t1 = (NT * (kz + 1)) / SKT;
    const int arow = tid >> 2, achk = tid & 3;
    const int b = bm + arow;

    f32x4 acc[2][4] = {};

    auto STAGE = [&](int buf, int t) {
        const int p0 = t << 5;
        #pragma unroll
        for (int r = 0; r < 2; ++r) {
            int n = (r * 256 + tid) >> 2;
            const u16* bsrc = Bt + (size_t)n * 8256 + p0 + (achk ^ (n & 3)) * 8;
            gload_lds16(bsrc,       (char*)&Bs[buf][0][0] + r * 4096 + wid * 1024);
            gload_lds16(bsrc + BLO, (char*)&Bs[buf][1][0] + r * 4096 + wid * 1024);
        }
        const int pp = p0 + achk * 8;
        u16 hi8[8];
        if (pp < 8192) {
            const float hf = bf2f(h[b * 128 + (pp >> 6)]);
            s16x8 zv = *(const s16x8*)&z[b * 64 + (pp & 63)];
            #pragma unroll
            for (int j = 0; j < 8; ++j) hi8[j] = f2bf(hf * bf2f((u16)zv[j]));
        } else {
            s16x8 zv = *(const s16x8*)&z[b * 64 + (pp - 8192)];
            #pragma unroll
            for (int j = 0; j < 8; ++j) hi8[j] = (u16)zv[j];
        }
        const int s = achk ^ (arow & 3);
        *(s16x8*)&As[buf][arow * 32 + s * 8] = *(s16x8*)hi8;
    };
    auto COMPUTE = [&](int buf) {
        s16x8 a[2];
        #pragma unroll
        for (int mi = 0; mi < 2; ++mi) {
            int row = wr * 32 + mi * 16 + (lane & 15);
            int s = (lane >> 4) ^ (row & 3);
            a[mi] = *(const s16x8*)&As[buf][row * 32 + s * 8];
        }
        #pragma unroll
        for (int ni = 0; ni < 4; ++ni) {
            int n = wc * 64 + ni * 16 + (lane & 15);
            int s = (lane >> 4) ^ (n & 3);
            s16x8 bh = *(const s16x8*)&Bs[buf][0][n * 32 + s * 8];
            s16x8 bl = *(const s16x8*)&Bs[buf][1][n * 32 + s * 8];
            #pragma unroll
            for (int mi = 0; mi < 2; ++mi) {
                acc[mi][ni] = MFMA(a[mi], bh, acc[mi][ni]);
                acc[mi][ni] = MFMA(a[mi], bl, acc[mi][ni]);
            }
        }
    };

    STAGE(0, t0);
    __syncthreads();
    const int nt = t1 - t0;
    for (int t = 0; t < nt; ++t) {
        if (t + 1 < nt) STAGE((t + 1) & 1, t0 + t + 1);
        COMPUTE(t & 1);
        __syncthreads();
    }

    #pragma unroll
    for (int mi = 0; mi < 2; ++mi)
    #pragma unroll
    for (int ni = 0; ni < 4; ++ni) {
        const int col = wc * 64 + ni * 16 + (lane & 15);
        #pragma unroll
        for (int j = 0; j < 4; ++j) {
            const int row = bm + wr * 32 + mi * 16 + (lane >> 4) * 4 + j;
            Cp[((size_t)kz * 2048 + row) * 128 + col] = acc[mi][ni][j];
        }
    }
}

// ---------------------------------------------------------------------------
// small fused kernels
// ---------------------------------------------------------------------------
__global__ __launch_bounds__(256)
void reduce_tanh(const float* __restrict__ Cp, u16* __restrict__ hout) {
    const int idx = blockIdx.x * 256 + threadIdx.x;      // 2048*128
    const size_t S = (size_t)2048 * 128;
    float s = 0.f;
    #pragma unroll
    for (int k = 0; k < 16; ++k) s += Cp[idx + k * S];
    hout[idx] = f2bf(fast_tanh(s));
}

__global__ __launch_bounds__(256)
void reduce_z(const float* __restrict__ zp, const float* __restrict__ bz,
              u16* __restrict__ zbf) {
    const int idx = blockIdx.x * 256 + threadIdx.x;      // 2048*64
    const size_t S = (size_t)2048 * 64;
    float s = bz[idx & 63];
    #pragma unroll
    for (int k = 0; k < 8; ++k) s += zp[idx + k * S];
    zbf[idx] = f2bf(s);
}

__global__ __launch_bounds__(256)
void h1_kernel(const float* __restrict__ c1, const float* __restrict__ t,
               u16* __restrict__ h1) {
    const int idx = blockIdx.x * 256 + threadIdx.x;      // 2048*128
    const int b = idx >> 7, o = idx & 127;
    h1[idx] = f2bf(fast_tanh(t[b] * c1[b * 256 + 128 + o] + c1[b * 256 + o]));
}

__global__ __launch_bounds__(256)
void out_kernel(const u16* __restrict__ h3, const u16* __restrict__ z,
                const float* __restrict__ W2, const float* __restrict__ t,
                const float* __restrict__ u, float* __restrict__ out) {
    __shared__ float sh[4][128];
    const int wv = threadIdx.x >> 6, l = threadIdx.x & 63;
    const int b = blockIdx.x * 4 + wv;
    sh[wv][l]      = bf2f(h3[b * 128 + l]);
    sh[wv][64 + l] = bf2f(h3[b * 128 + 64 + l]);
    __syncthreads();
    const float* wrow = &W2[(size_t)l * LDP + 33280];
    float acc = wrow[0];
    #pragma unroll 8
    for (int i = 0; i < 128; ++i) acc = fmaf(sh[wv][i], wrow[1 + i], acc);
    float p = bf2f(z[b * 64 + l]) * acc;
    #pragma unroll
    for (int off = 32; off > 0; off >>= 1) p += __shfl_down(p, off);
    if (l == 0) out[b] = u[b * 128] + t[b] * p;
}

// ---------------------------------------------------------------------------
extern "C" void kernel_launch(void* const* d_in, const int* in_sizes, int n_in,
                              void* d_out, int out_size, void* d_ws, size_t ws_size,
                              hipStream_t stream)
{
    const float* t   = (const float*)d_in[0];
    const float* u   = (const float*)d_in[1];
    const float* bw0 = (const float*)d_in[2];
    const float* bb0 = (const float*)d_in[3];
    const float* bw1 = (const float*)d_in[4];
    const float* bb1 = (const float*)d_in[5];
    const float* bw2 = (const float*)d_in[6];
    const float* bb2 = (const float*)d_in[7];
    const float* bw3 = (const float*)d_in[8];
    const float* bb3 = (const float*)d_in[9];
    const float* bw4 = (const float*)d_in[10];
    const float* bb4 = (const float*)d_in[11];
    const float* W1  = (const float*)d_in[12];
    const float* W2  = (const float*)d_in[13];
    float* out = (float*)d_out;

    // ---- workspace layout (bytes). Weight pairs: lo at +half. Acts plain.
    char* base = (char*)d_ws;
    u16*   bw1t = (u16*)(base);                  // 4 MB  [0, 4194304)
    u16*   bw2t = (u16*)(base + 4194304);        // 4 MB
    u16*   bw3t = (u16*)(base + 8388608);        // 4 MB
    u16*   ubf  = (u16*)(base + 12582912);       // 512 KB
    u16*   bw0t = (u16*)(base + 13107200);       // 512 KB
    u16*   actA = (u16*)(base + 13631488);       // 4 MB
    u16*   actB = (u16*)(base + 17825792);       // 4 MB
    u16*   Wc1t = (u16*)(base + 22020096);       // 64 KB
    u16*   BWt  = (u16*)(base + 22085632);       // 256 KB
    float* bz   = (float*)(base + 22347776);     // 256 B
    u16*   z    = (u16*)(base + 22348032);       // 256 KB
    u16*   h1   = (u16*)(base + 22610176);       // 512 KB
    u16*   h2   = (u16*)(base + 23134464);       // 512 KB
    u16*   h3   = (u16*)(base + 23658752);       // 512 KB
    u16*   Bt2  = (u16*)(base + 24183040);       // 4,227,072
    u16*   Bt3  = (u16*)(base + 28410112);       // 4,227,072 (end 32,637,184)
    // overlays (stream-ordered liveness):
    float* zc = (float*)(base);                  // 4 MB over bw1t (dead after L1)
    float* c1 = (float*)(base + 4194304);        // 2 MB over bw2t (dead after L2)
    float* Cp = (float*)(base);                  // 16.78 MB over bw1-3t/ubf/bw0t/actA[:3MB]

    dim3 blk(256);
    // ---- prep
    cvt_plain<<<128, blk, 0, stream>>>(u, ubf, 2048 * 128);
    transpose_cvt<<<dim3(16, 2),  blk, 0, stream>>>(bw0, 1024, bw0t, 128,  1024 * 128);
    transpose_cvt<<<dim3(16, 16), blk, 0, stream>>>(bw1, 1024, bw1t, 1024, 1024 * 1024);
    transpose_cvt<<<dim3(16, 16), blk, 0, stream>>>(bw2, 1024, bw2t, 1024, 1024 * 1024);
    transpose_cvt<<<dim3(16, 16), blk, 0, stream>>>(bw3, 1024, bw3t, 1024, 1024 * 1024);
    transpose_cvt<<<dim3(4, 1),   blk, 0, stream>>>(W2, LDP, Wc1t, 64, 256 * 64);
    bw_kernel<<<256, blk, 0, stream>>>(bw4, W1, BWt);
    bz_kernel<<<1, 64, 0, stream>>>(bb4, W1, bz);
    gather_trunk<<<129, blk, 0, stream>>>(W2, Bt2, 384, 256);
    gather_trunk<<<129, blk, 0, stream>>>(W2, Bt3, 16896, 16768);

    // ---- branch MLP (bw4@W1 folded into BWt); 64x64 tiles, 512 blocks
    mfma_gemm<1, 1><<<dim3(16, 32, 1), blk, 0, stream>>>(
        ubf, 128, bw0t, 1024 * 128, 128, bb0, actA, 1024, 2048, 128, 1);
    mfma_gemm<1, 1><<<dim3(16, 32, 1), blk, 0, stream>>>(
        actA, 1024, bw1t, 1024 * 1024, 1024, bb1, actB, 1024, 2048, 1024, 1);
    mfma_gemm<1, 1><<<dim3(16, 32, 1), blk, 0, stream>>>(
        actB, 1024, bw2t, 1024 * 1024, 1024, bb2, actA, 1024, 2048, 1024, 1);
    mfma_gemm<1, 1><<<dim3(16, 32, 1), blk, 0, stream>>>(
        actA, 1024, bw3t, 1024 * 1024, 1024, bb3, actB, 1024, 2048, 1024, 1);
    // ---- z = actB @ BW (+bz), split-K=8 (partials into zc over bw1t)
    mfma_gemm<0, 3><<<dim3(1, 32, 8), blk, 0, stream>>>(
        actB, 1024, BWt, 64 * 1024, 1024, nullptr, zc, 64, 2048, 1024, 8);
    reduce_z<<<512, blk, 0, stream>>>(zc, bz, z);
    // ---- trunk layer 1: c1 = z @ W2[:,0:256] (f32), then h1
    mfma_gemm<0, 0><<<dim3(4, 32, 1), blk, 0, stream>>>(
        z, 64, Wc1t, 256 * 64, 64, nullptr, c1, 256, 2048, 64, 1);
    h1_kernel<<<1024, blk, 0, stream>>>(c1, t, h1);
    // ---- trunk layers 2,3 (split-K=16, 512 blocks)
    trunk_mfma<<<dim3(32, 16), blk, 0, stream>>>(h1, z, Bt2, Cp);
    reduce_tanh<<<1024, blk, 0, stream>>>(Cp, h2);
    trunk_mfma<<<dim3(32, 16), blk, 0, stream>>>(h2, z, Bt3, Cp);
    reduce_tanh<<<1024, blk, 0, stream>>>(Cp, h3);
    // ---- trunk layer 4 + combine
    out_kernel<<<512, blk, 0, stream>>>(h3, z, W2, t, u, out);
}

// Round 6
// 232.784 us; speedup vs baseline: 3.2187x; 1.0730x over previous
//
#include <hip/hip_runtime.h>
#include <hip/hip_bf16.h>
#include <stdint.h>

typedef unsigned short u16;
typedef unsigned int   u32;
typedef short s16x8 __attribute__((ext_vector_type(8)));
typedef float f32x4 __attribute__((ext_vector_type(4)));

#define LDP 33409

__device__ __forceinline__ u16 f2bf(float f) {
    union { float f; u32 u; } v; v.f = f;
    u32 r = v.u + 0x7fffu + ((v.u >> 16) & 1u);
    return (u16)(r >> 16);
}
__device__ __forceinline__ float bf2f(u16 h) {
    union { u32 u; float f; } v; v.u = ((u32)h) << 16;
    return v.f;
}
__device__ __forceinline__ float fast_tanh(float x) {
    float e = __expf(2.0f * x);
    return 1.0f - 2.0f / (e + 1.0f);
}
__device__ __forceinline__ f32x4 MFMA(s16x8 a, s16x8 b, f32x4 c) {
    return __builtin_amdgcn_mfma_f32_16x16x32_bf16(a, b, c, 0, 0, 0);
}
__device__ __forceinline__ void gload_lds16(const void* g, void* l) {
    __builtin_amdgcn_global_load_lds(
        (const __attribute__((address_space(1))) u32*)(uintptr_t)g,
        (__attribute__((address_space(3))) u32*)(uintptr_t)l, 16, 0, 0);
}

// ---------------------------------------------------------------------------
// prep kernels (all 1-term bf16 now)
// ---------------------------------------------------------------------------

__global__ __launch_bounds__(256)
void cvt_plain(const float* __restrict__ s, u16* __restrict__ d, int n) {
    int i = (blockIdx.x * 256 + threadIdx.x) * 8;
    if (i >= n) return;
    float4 a = *(const float4*)&s[i];
    float4 b = *(const float4*)&s[i + 4];
    uint4 o;
    o.x = (u32)f2bf(a.x) | ((u32)f2bf(a.y) << 16);
    o.y = (u32)f2bf(a.z) | ((u32)f2bf(a.w) << 16);
    o.z = (u32)f2bf(b.x) | ((u32)f2bf(b.y) << 16);
    o.w = (u32)f2bf(b.z) | ((u32)f2bf(b.w) << 16);
    *(uint4*)&d[i] = o;
}

// generic 64x64-tiled transpose+cvt: dst[c][r] = src[r][c]
__global__ __launch_bounds__(256)
void transpose_cvt(const float* __restrict__ src, int ldsrc,
                   u16* __restrict__ dst, int lddst) {
    __shared__ float tile[64][65];
    const int rb = blockIdx.y * 64, cb = blockIdx.x * 64;
    for (int i = threadIdx.x; i < 64 * 64; i += 256) {
        int r = i >> 6, c = i & 63;
        tile[r][c] = src[(size_t)(rb + r) * ldsrc + cb + c];
    }
    __syncthreads();
    for (int i = threadIdx.x; i < 64 * 64; i += 256) {
        int c = i >> 6, r = i & 63;
        dst[(size_t)(cb + c) * lddst + rb + r] = f2bf(tile[r][c]);
    }
}

// three 1024x1024 transposes in one dispatch (grid z = 0..2)
__global__ __launch_bounds__(256)
void transpose3(const float* __restrict__ s0, const float* __restrict__ s1,
                const float* __restrict__ s2,
                u16* __restrict__ d0, u16* __restrict__ d1, u16* __restrict__ d2) {
    const float* src = blockIdx.z == 0 ? s0 : (blockIdx.z == 1 ? s1 : s2);
    u16*        dst  = blockIdx.z == 0 ? d0 : (blockIdx.z == 1 ? d1 : d2);
    __shared__ float tile[64][65];
    const int rb = blockIdx.y * 64, cb = blockIdx.x * 64;
    for (int i = threadIdx.x; i < 64 * 64; i += 256) {
        int r = i >> 6, c = i & 63;
        tile[r][c] = src[(size_t)(rb + r) * 1024 + cb + c];
    }
    __syncthreads();
    for (int i = threadIdx.x; i < 64 * 64; i += 256) {
        int c = i >> 6, r = i & 63;
        dst[(size_t)(cb + c) * 1024 + rb + r] = f2bf(tile[r][c]);
    }
}

// gathered trunk weight view: Bt[layer][n][p], n<128, p<8256  (grid y = layer)
__global__ __launch_bounds__(256)
void gather_trunk(const float* __restrict__ W2, u16* __restrict__ Btb) {
    const int layer = blockIdx.y;
    u16* Bt = Btb + (size_t)layer * 128 * 8256;
    const int colbase = layer ? 16896 : 384, biasbase = layer ? 16768 : 256;
    __shared__ float tile[64][130];
    const int pb = blockIdx.x * 64;
    for (int i = threadIdx.x; i < 64 * 128; i += 256) {
        int p = pb + (i >> 7), n = i & 127;
        float v = (p < 8192)
            ? W2[(size_t)(p & 63) * LDP + colbase + (size_t)(p >> 6) * 128 + n]
            : W2[(size_t)(p - 8192) * LDP + biasbase + n];
        tile[i >> 7][n] = v;
    }
    __syncthreads();
    for (int i = threadIdx.x; i < 64 * 128; i += 256) {
        int n = i >> 6, dp = i & 63;
        Bt[(size_t)n * 8256 + pb + dp] = f2bf(tile[dp][n]);
    }
}

// exact-f32: BWt[n][k] = (bw4 @ W1)[k][n]
__global__ __launch_bounds__(256)
void bw_kernel(const float* __restrict__ bw4, const float* __restrict__ W1,
               u16* __restrict__ BWt) {
    const int n = threadIdx.x & 63;
    const int k = blockIdx.x * 4 + (threadIdx.x >> 6);
    float a = 0.f;
    for (int j = 0; j < 1024; ++j) a = fmaf(bw4[(size_t)k * 1024 + j], W1[j * 64 + n], a);
    BWt[(size_t)n * 1024 + k] = f2bf(a);
}

__global__ __launch_bounds__(64)
void bz_kernel(const float* __restrict__ bb4, const float* __restrict__ W1,
               float* __restrict__ bz) {
    int n = threadIdx.x;
    float a = 0.f;
    for (int j = 0; j < 1024; ++j) a = fmaf(bb4[j], W1[j * 64 + n], a);
    bz[n] = a;
}

// ---------------------------------------------------------------------------
// 128x128-tile bf16 MFMA GEMM (m97 structure): C = act(A @ Bt^T + bias)
// 4 waves (2x2), each wave 64x64 via 4x4 16x16x32 frags, BK=32, dbuf LDS.
// OUT: 0 = f32, 1 = bf16
// ---------------------------------------------------------------------------
template<int ACT, int OUT>
__global__ __launch_bounds__(256, 2)
void gemm128(const u16* __restrict__ A, int lda,
             const u16* __restrict__ Bt, int ldb,
             const float* __restrict__ bias,
             void* __restrict__ Cout, int ldc, int K)
{
    __shared__ __align__(16) u16 As[2][128 * 32];
    __shared__ __align__(16) u16 Bs[2][128 * 32];
    const int tid = threadIdx.x, lane = tid & 63, wid = tid >> 6;
    const int wr = wid >> 1, wc = wid & 1;
    const int bn = blockIdx.x * 128, bm = blockIdx.y * 128;
    const int NT = K >> 5;
    const int ck = tid & 3;
    f32x4 acc[4][4] = {};

    auto STAGE = [&](int buf, int t) {
        const int k0 = t << 5;
        #pragma unroll
        for (int r = 0; r < 2; ++r) {
            const int row = (r * 256 + tid) >> 2;
            gload_lds16(A + (size_t)(bm + row) * lda + k0 + (ck ^ (row & 3)) * 8,
                        (char*)As[buf] + r * 4096 + wid * 1024);
            gload_lds16(Bt + (size_t)(bn + row) * ldb + k0 + (ck ^ (row & 3)) * 8,
                        (char*)Bs[buf] + r * 4096 + wid * 1024);
        }
    };
    auto COMPUTE = [&](int buf) {
        s16x8 a[4], b[4];
        #pragma unroll
        for (int mi = 0; mi < 4; ++mi) {
            int row = wr * 64 + mi * 16 + (lane & 15);
            int s = (lane >> 4) ^ (row & 3);
            a[mi] = *(const s16x8*)&As[buf][row * 32 + s * 8];
        }
        #pragma unroll
        for (int ni = 0; ni < 4; ++ni) {
            int n = wc * 64 + ni * 16 + (lane & 15);
            int s = (lane >> 4) ^ (n & 3);
            b[ni] = *(const s16x8*)&Bs[buf][n * 32 + s * 8];
        }
        #pragma unroll
        for (int mi = 0; mi < 4; ++mi)
        #pragma unroll
        for (int ni = 0; ni < 4; ++ni)
            acc[mi][ni] = MFMA(a[mi], b[ni], acc[mi][ni]);
    };

    STAGE(0, 0);
    __syncthreads();
    for (int t = 0; t < NT; ++t) {
        if (t + 1 < NT) STAGE((t + 1) & 1, t + 1);
        COMPUTE(t & 1);
        __syncthreads();
    }

    #pragma unroll
    for (int mi = 0; mi < 4; ++mi)
    #pragma unroll
    for (int ni = 0; ni < 4; ++ni) {
        const int col = bn + wc * 64 + ni * 16 + (lane & 15);
        const float bv = bias ? bias[col] : 0.f;
        #pragma unroll
        for (int jj = 0; jj < 4; ++jj) {
            const int row = bm + wr * 64 + mi * 16 + (lane >> 4) * 4 + jj;
            float v = acc[mi][ni][jj] + bv;
            if (ACT) v = fast_tanh(v);
            if (OUT == 0) ((float*)Cout)[(size_t)row * ldc + col] = v;
            else          ((u16*)Cout)[(size_t)row * ldc + col] = f2bf(v);
        }
    }
}

// ---------------------------------------------------------------------------
// z-GEMM: zc[kz][2048][64] partials = actB[2048,1024] @ BWt[64,1024]^T, SK=8
// 64x64 tile, 4 waves 2x2 of 2x2 frags.
// ---------------------------------------------------------------------------
__global__ __launch_bounds__(256, 2)
void zgemm(const u16* __restrict__ A, const u16* __restrict__ Bt,
           float* __restrict__ zc)
{
    __shared__ __align__(16) u16 As[2][64 * 32];
    __shared__ __align__(16) u16 Bs[2][64 * 32];
    const int tid = threadIdx.x, lane = tid & 63, wid = tid >> 6;
    const int wr = wid >> 1, wc = wid & 1;
    const int bm = blockIdx.y * 64, kz = blockIdx.z;
    const int t0 = kz * 4, nt = 4;        // K=1024, NT=32, SK=8
    const int arow = tid >> 2, ck = tid & 3;
    const u16* aSrc = A + (size_t)(bm + arow) * 1024 + (ck ^ (arow & 3)) * 8;
    const u16* bSrc = Bt + (size_t)arow * 1024 + (ck ^ (arow & 3)) * 8;
    f32x4 acc[2][2] = {};

    auto STAGE = [&](int buf, int t) {
        const int k0 = t << 5;
        gload_lds16(aSrc + k0, (char*)As[buf] + wid * 1024);
        gload_lds16(bSrc + k0, (char*)Bs[buf] + wid * 1024);
    };
    auto COMPUTE = [&](int buf) {
        s16x8 a[2];
        #pragma unroll
        for (int mi = 0; mi < 2; ++mi) {
            int row = wr * 32 + mi * 16 + (lane & 15);
            int s = (lane >> 4) ^ (row & 3);
            a[mi] = *(const s16x8*)&As[buf][row * 32 + s * 8];
        }
        #pragma unroll
        for (int ni = 0; ni < 2; ++ni) {
            int n = wc * 32 + ni * 16 + (lane & 15);
            int s = (lane >> 4) ^ (n & 3);
            s16x8 b = *(const s16x8*)&Bs[buf][n * 32 + s * 8];
            #pragma unroll
            for (int mi = 0; mi < 2; ++mi)
                acc[mi][ni] = MFMA(a[mi], b, acc[mi][ni]);
        }
    };

    STAGE(0, t0);
    __syncthreads();
    for (int t = 0; t < nt; ++t) {
        if (t + 1 < nt) STAGE((t + 1) & 1, t0 + t + 1);
        COMPUTE(t & 1);
        __syncthreads();
    }
    #pragma unroll
    for (int mi = 0; mi < 2; ++mi)
    #pragma unroll
    for (int ni = 0; ni < 2; ++ni) {
        const int col = wc * 32 + ni * 16 + (lane & 15);
        #pragma unroll
        for (int jj = 0; jj < 4; ++jj) {
            const int row = bm + wr * 32 + mi * 16 + (lane >> 4) * 4 + jj;
            zc[((size_t)kz * 2048 + row) * 64 + col] = acc[mi][ni][jj];
        }
    }
}

// ---------------------------------------------------------------------------
// Trunk GEMM: Cp[kz][2048][128] partials; A generated on the fly (bf16):
//   p<8192: h[b,p>>6]*z[b,p&63] ; else z[b,p-8192].  K=8256, SK=16.
// 128(M)x128(N) tile, 4 waves, 4x4 frags.  z fragments hoisted to registers.
// ---------------------------------------------------------------------------
__global__ __launch_bounds__(256, 2)
void trunk128(const u16* __restrict__ h, const u16* __restrict__ z,
              const u16* __restrict__ Bt, float* __restrict__ Cp)
{
    constexpr int NT = 258, SKT = 16;
    __shared__ __align__(16) u16 As[2][128 * 32];
    __shared__ __align__(16) u16 Bs[2][128 * 32];
    const int tid = threadIdx.x, lane = tid & 63, wid = tid >> 6;
    const int wr = wid >> 1, wc = wid & 1;
    const int bm = blockIdx.x * 128, kz = blockIdx.y;
    const int t0 = (NT * kz) / SKT, t1 = (NT * (kz + 1)) / SKT;
    const int ck = tid & 3;
    // A-gen: thread owns row (tid>>1), chunks c0,c1; z frags preloaded
    const int arow = tid >> 1;
    const int b = bm + arow;
    const int c0 = (tid & 1) * 2, c1 = c0 + 1;
    const s16x8 zA0 = *(const s16x8*)&z[b * 64 + c0 * 8];
    const s16x8 zA1 = *(const s16x8*)&z[b * 64 + c1 * 8];
    const s16x8 zB0 = *(const s16x8*)&z[b * 64 + 32 + c0 * 8];
    const s16x8 zB1 = *(const s16x8*)&z[b * 64 + 32 + c1 * 8];
    const int s0 = (c0 ^ (arow & 3)) * 8, s1 = (c1 ^ (arow & 3)) * 8;
    f32x4 acc[4][4] = {};

    auto STAGE = [&](int buf, int t) {
        const int p0 = t << 5;
        #pragma unroll
        for (int r = 0; r < 2; ++r) {
            const int n = (r * 256 + tid) >> 2;
            gload_lds16(Bt + (size_t)n * 8256 + p0 + (ck ^ (n & 3)) * 8,
                        (char*)Bs[buf] + r * 4096 + wid * 1024);
        }
        const s16x8 za = (p0 & 32) ? zB0 : zA0;
        const s16x8 zb = (p0 & 32) ? zB1 : zA1;
        u16 o0[8], o1[8];
        if (p0 < 8192) {
            const float hf = bf2f(h[b * 128 + (p0 >> 6)]);
            #pragma unroll
            for (int j = 0; j < 8; ++j) {
                o0[j] = f2bf(hf * bf2f((u16)za[j]));
                o1[j] = f2bf(hf * bf2f((u16)zb[j]));
            }
        } else {
            #pragma unroll
            for (int j = 0; j < 8; ++j) { o0[j] = (u16)za[j]; o1[j] = (u16)zb[j]; }
        }
        *(s16x8*)&As[buf][arow * 32 + s0] = *(s16x8*)o0;
        *(s16x8*)&As[buf][arow * 32 + s1] = *(s16x8*)o1;
    };
    auto COMPUTE = [&](int buf) {
        s16x8 a[4], bb[4];
        #pragma unroll
        for (int mi = 0; mi < 4; ++mi) {
            int row = wr * 64 + mi * 16 + (lane & 15);
            int s = (lane >> 4) ^ (row & 3);
            a[mi] = *(const s16x8*)&As[buf][row * 32 + s * 8];
        }
        #pragma unroll
        for (int ni = 0; ni < 4; ++ni) {
            int n = wc * 64 + ni * 16 + (lane & 15);
            int s = (lane >> 4) ^ (n & 3);
            bb[ni] = *(const s16x8*)&Bs[buf][n * 32 + s * 8];
        }
        #pragma unroll
        for (int mi = 0; mi < 4; ++mi)
        #pragma unroll
        for (int ni = 0; ni < 4; ++ni)
            acc[mi][ni] = MFMA(a[mi], bb[ni], acc[mi][ni]);
    };

    STAGE(0, t0);
    __syncthreads();
    const int nt = t1 - t0;
    for (int t = 0; t < nt; ++t) {
        if (t + 1 < nt) STAGE((t + 1) & 1, t0 + t + 1);
        COMPUTE(t & 1);
        __syncthreads();
    }

    #pragma unroll
    for (int mi = 0; mi < 4; ++mi)
    #pragma unroll
    for (int ni = 0; ni < 4; ++ni) {
        const int col = wc * 64 + ni * 16 + (lane & 15);
        #pragma unroll
        for (int jj = 0; jj < 4; ++jj) {
            const int row = bm + wr * 64 + mi * 16 + (lane >> 4) * 4 + jj;
            Cp[((size_t)kz * 2048 + row) * 128 + col] = acc[mi][ni][jj];
        }
    }
}

// ---------------------------------------------------------------------------
// small fused kernels
// ---------------------------------------------------------------------------
__global__ __launch_bounds__(256)
void reduce_tanh(const float* __restrict__ Cp, u16* __restrict__ hout) {
    const int idx = blockIdx.x * 256 + threadIdx.x;      // 2048*128
    const size_t S = (size_t)2048 * 128;
    float s = 0.f;
    #pragma unroll
    for (int k = 0; k < 16; ++k) s += Cp[idx + k * S];
    hout[idx] = f2bf(fast_tanh(s));
}

__global__ __launch_bounds__(256)
void reduce_z(const float* __restrict__ zp, const float* __restrict__ bz,
              u16* __restrict__ zbf) {
    const int idx = blockIdx.x * 256 + threadIdx.x;      // 2048*64
    const size_t S = (size_t)2048 * 64;
    float s = bz[idx & 63];
    #pragma unroll
    for (int k = 0; k < 8; ++k) s += zp[idx + k * S];
    zbf[idx] = f2bf(s);
}

__global__ __launch_bounds__(256)
void h1_kernel(const float* __restrict__ c1, const float* __restrict__ t,
               u16* __restrict__ h1) {
    const int idx = blockIdx.x * 256 + threadIdx.x;      // 2048*128
    const int b = idx >> 7, o = idx & 127;
    h1[idx] = f2bf(fast_tanh(t[b] * c1[b * 256 + 128 + o] + c1[b * 256 + o]));
}

// layer-3 reduce+tanh fused with trunk L4 + final combine (one wave / sample)
__global__ __launch_bounds__(256)
void reduce_out(const float* __restrict__ Cp, const u16* __restrict__ z,
                const float* __restrict__ W2, const float* __restrict__ t,
                const float* __restrict__ u, float* __restrict__ out)
{
    __shared__ float sh[4][128];
    const int wv = threadIdx.x >> 6, l = threadIdx.x & 63;
    const int b = blockIdx.x * 4 + wv;
    const size_t S = (size_t)2048 * 128;
    #pragma unroll
    for (int e = l; e < 128; e += 64) {
        float s = 0.f;
        #pragma unroll
        for (int k = 0; k < 16; ++k) s += Cp[k * S + (size_t)b * 128 + e];
        sh[wv][e] = fast_tanh(s);
    }
    __syncthreads();
    const float* wrow = &W2[(size_t)l * LDP + 33280];
    float acc = wrow[0];
    #pragma unroll 8
    for (int i = 0; i < 128; ++i) acc = fmaf(sh[wv][i], wrow[1 + i], acc);
    float p = bf2f(z[b * 64 + l]) * acc;
    #pragma unroll
    for (int off = 32; off > 0; off >>= 1) p += __shfl_down(p, off);
    if (l == 0) out[b] = u[b * 128] + t[b] * p;
}

// ---------------------------------------------------------------------------
extern "C" void kernel_launch(void* const* d_in, const int* in_sizes, int n_in,
                              void* d_out, int out_size, void* d_ws, size_t ws_size,
                              hipStream_t stream)
{
    const float* t   = (const float*)d_in[0];
    const float* u   = (const float*)d_in[1];
    const float* bw0 = (const float*)d_in[2];
    const float* bb0 = (const float*)d_in[3];
    const float* bw1 = (const float*)d_in[4];
    const float* bb1 = (const float*)d_in[5];
    const float* bw2 = (const float*)d_in[6];
    const float* bb2 = (const float*)d_in[7];
    const float* bw3 = (const float*)d_in[8];
    const float* bb3 = (const float*)d_in[9];
    const float* bw4 = (const float*)d_in[10];
    const float* bb4 = (const float*)d_in[11];
    const float* W1  = (const float*)d_in[12];
    const float* W2  = (const float*)d_in[13];
    float* out = (float*)d_out;

    // ---- workspace layout (bytes). All weights/acts plain bf16.
    char* base = (char*)d_ws;
    u16*   bw1t = (u16*)(base);                  // 2 MB
    u16*   bw2t = (u16*)(base + 2097152);        // 2 MB
    u16*   bw3t = (u16*)(base + 4194304);        // 2 MB
    u16*   actA = (u16*)(base + 6291456);        // 4 MB
    u16*   actB = (u16*)(base + 10485760);       // 4 MB
    u16*   ubf  = (u16*)(base + 14680064);       // 512 KB
    u16*   bw0t = (u16*)(base + 15204352);       // 256 KB
    u16*   Wc1t = (u16*)(base + 15466496);       // 32 KB
    u16*   BWt  = (u16*)(base + 15499264);       // 128 KB
    float* bz   = (float*)(base + 15630336);     // 256 B
    // [everything above is dead before trunk layer 2 -> Cp overlays it]
    u16*   z    = (u16*)(base + 16777216);       // 256 KB
    u16*   h1   = (u16*)(base + 17039360);       // 512 KB
    u16*   h2   = (u16*)(base + 17563648);       // 512 KB
    u16*   Bt   = (u16*)(base + 18087936);       // 2 x 128 x 8256 x 2 = 4,227,072
    // overlays (stream-ordered liveness):
    float* zc = (float*)(base);                  // 4 MB   (z-gemm .. reduce_z)
    float* c1 = (float*)(base);                  // 2 MB   (L1 .. h1)
    float* Cp = (float*)(base);                  // 16.78 MB (trunk partials)

    dim3 blk(256);
    // ---- prep
    cvt_plain<<<128, blk, 0, stream>>>(u, ubf, 2048 * 128);
    transpose_cvt<<<dim3(16, 2), blk, 0, stream>>>(bw0, 1024, bw0t, 128);
    transpose3<<<dim3(16, 16, 3), blk, 0, stream>>>(bw1, bw2, bw3, bw1t, bw2t, bw3t);
    transpose_cvt<<<dim3(4, 1), blk, 0, stream>>>(W2, LDP, Wc1t, 64);
    bw_kernel<<<256, blk, 0, stream>>>(bw4, W1, BWt);
    bz_kernel<<<1, 64, 0, stream>>>(bb4, W1, bz);
    gather_trunk<<<dim3(129, 2), blk, 0, stream>>>(W2, Bt);

    // ---- branch MLP (bw4@W1 folded into BWt); 128x128 tiles
    gemm128<1, 1><<<dim3(8, 16), blk, 0, stream>>>(ubf,  128,  bw0t, 128,  bb0, actA, 1024, 128);
    gemm128<1, 1><<<dim3(8, 16), blk, 0, stream>>>(actA, 1024, bw1t, 1024, bb1, actB, 1024, 1024);
    gemm128<1, 1><<<dim3(8, 16), blk, 0, stream>>>(actB, 1024, bw2t, 1024, bb2, actA, 1024, 1024);
    gemm128<1, 1><<<dim3(8, 16), blk, 0, stream>>>(actA, 1024, bw3t, 1024, bb3, actB, 1024, 1024);
    // ---- z = actB @ BW (+bz), split-K=8
    zgemm<<<dim3(1, 32, 8), blk, 0, stream>>>(actB, BWt, zc);
    reduce_z<<<512, blk, 0, stream>>>(zc, bz, z);
    // ---- trunk layer 1: c1 = z @ W2[:,0:256] (f32), then h1
    gemm128<0, 0><<<dim3(2, 16), blk, 0, stream>>>(z, 64, Wc1t, 64, nullptr, c1, 256, 64);
    h1_kernel<<<1024, blk, 0, stream>>>(c1, t, h1);
    // ---- trunk layers 2,3 (128x128 tiles, split-K=16)
    trunk128<<<dim3(16, 16), blk, 0, stream>>>(h1, z, Bt, Cp);
    reduce_tanh<<<1024, blk, 0, stream>>>(Cp, h2);
    trunk128<<<dim3(16, 16), blk, 0, stream>>>(h2, z, Bt + (size_t)128 * 8256, Cp);
    // ---- layer-3 reduce + trunk L4 + combine (fused)
    reduce_out<<<512, blk, 0, stream>>>(Cp, z, W2, t, u, out);
}

// Round 7
// 187.970 us; speedup vs baseline: 3.9861x; 1.2384x over previous
//
#include <hip/hip_runtime.h>
#include <hip/hip_bf16.h>
#include <stdint.h>

typedef unsigned short u16;
typedef unsigned int   u32;
typedef short s16x8 __attribute__((ext_vector_type(8)));
typedef float f32x4 __attribute__((ext_vector_type(4)));

#define LDP 33409

__device__ __forceinline__ u16 f2bf(float f) {
    union { float f; u32 u; } v; v.f = f;
    u32 r = v.u + 0x7fffu + ((v.u >> 16) & 1u);
    return (u16)(r >> 16);
}
__device__ __forceinline__ float bf2f(u16 h) {
    union { u32 u; float f; } v; v.u = ((u32)h) << 16;
    return v.f;
}
__device__ __forceinline__ float fast_tanh(float x) {
    float e = __expf(2.0f * x);
    return 1.0f - 2.0f / (e + 1.0f);
}
__device__ __forceinline__ f32x4 MFMA(s16x8 a, s16x8 b, f32x4 c) {
    return __builtin_amdgcn_mfma_f32_16x16x32_bf16(a, b, c, 0, 0, 0);
}
__device__ __forceinline__ void gload_lds16(const void* g, void* l) {
    __builtin_amdgcn_global_load_lds(
        (const __attribute__((address_space(1))) u32*)(uintptr_t)g,
        (__attribute__((address_space(3))) u32*)(uintptr_t)l, 16, 0, 0);
}

// ---------------------------------------------------------------------------
// prep kernels
// ---------------------------------------------------------------------------

__global__ __launch_bounds__(256)
void cvt_plain(const float* __restrict__ s, u16* __restrict__ d, int n) {
    int i = (blockIdx.x * 256 + threadIdx.x) * 8;
    if (i >= n) return;
    float4 a = *(const float4*)&s[i];
    float4 b = *(const float4*)&s[i + 4];
    uint4 o;
    o.x = (u32)f2bf(a.x) | ((u32)f2bf(a.y) << 16);
    o.y = (u32)f2bf(a.z) | ((u32)f2bf(a.w) << 16);
    o.z = (u32)f2bf(b.x) | ((u32)f2bf(b.y) << 16);
    o.w = (u32)f2bf(b.z) | ((u32)f2bf(b.w) << 16);
    *(uint4*)&d[i] = o;
}

__global__ __launch_bounds__(256)
void transpose_cvt(const float* __restrict__ src, int ldsrc,
                   u16* __restrict__ dst, int lddst) {
    __shared__ float tile[64][65];
    const int rb = blockIdx.y * 64, cb = blockIdx.x * 64;
    for (int i = threadIdx.x; i < 64 * 64; i += 256) {
        int r = i >> 6, c = i & 63;
        tile[r][c] = src[(size_t)(rb + r) * ldsrc + cb + c];
    }
    __syncthreads();
    for (int i = threadIdx.x; i < 64 * 64; i += 256) {
        int c = i >> 6, r = i & 63;
        dst[(size_t)(cb + c) * lddst + rb + r] = f2bf(tile[r][c]);
    }
}

// three 1024x1024 transposes in one dispatch (grid z = 0..2)
__global__ __launch_bounds__(256)
void transpose3(const float* __restrict__ s0, const float* __restrict__ s1,
                const float* __restrict__ s2,
                u16* __restrict__ d0, u16* __restrict__ d1, u16* __restrict__ d2) {
    const float* src = blockIdx.z == 0 ? s0 : (blockIdx.z == 1 ? s1 : s2);
    u16*        dst  = blockIdx.z == 0 ? d0 : (blockIdx.z == 1 ? d1 : d2);
    __shared__ float tile[64][65];
    const int rb = blockIdx.y * 64, cb = blockIdx.x * 64;
    for (int i = threadIdx.x; i < 64 * 64; i += 256) {
        int r = i >> 6, c = i & 63;
        tile[r][c] = src[(size_t)(rb + r) * 1024 + cb + c];
    }
    __syncthreads();
    for (int i = threadIdx.x; i < 64 * 64; i += 256) {
        int c = i >> 6, r = i & 63;
        dst[(size_t)(cb + c) * 1024 + rb + r] = f2bf(tile[r][c]);
    }
}

// gathered trunk weight view: Bt[layer][n][p], n<128, p<8256
__global__ __launch_bounds__(256)
void gather_trunk(const float* __restrict__ W2, u16* __restrict__ Btb) {
    const int layer = blockIdx.y;
    u16* Bt = Btb + (size_t)layer * 128 * 8256;
    const int colbase = layer ? 16896 : 384, biasbase = layer ? 16768 : 256;
    __shared__ float tile[64][130];
    const int pb = blockIdx.x * 64;
    for (int i = threadIdx.x; i < 64 * 128; i += 256) {
        int p = pb + (i >> 7), n = i & 127;
        float v = (p < 8192)
            ? W2[(size_t)(p & 63) * LDP + colbase + (size_t)(p >> 6) * 128 + n]
            : W2[(size_t)(p - 8192) * LDP + biasbase + n];
        tile[i >> 7][n] = v;
    }
    __syncthreads();
    for (int i = threadIdx.x; i < 64 * 128; i += 256) {
        int n = i >> 6, dp = i & 63;
        Bt[(size_t)n * 8256 + pb + dp] = f2bf(tile[dp][n]);
    }
}

// BWt[n][k] = (bw4 @ W1)[k][n] (exact f32); block 256 computes bz = bb4 @ W1
__global__ __launch_bounds__(256)
void bw_bz(const float* __restrict__ bw4, const float* __restrict__ W1,
           const float* __restrict__ bb4, u16* __restrict__ BWt,
           float* __restrict__ bz) {
    if (blockIdx.x == 256) {
        int n = threadIdx.x;
        if (n < 64) {
            float a = 0.f;
            for (int j = 0; j < 1024; ++j) a = fmaf(bb4[j], W1[j * 64 + n], a);
            bz[n] = a;
        }
        return;
    }
    const int n = threadIdx.x & 63;
    const int k = blockIdx.x * 4 + (threadIdx.x >> 6);
    float a = 0.f;
    for (int j = 0; j < 1024; ++j) a = fmaf(bw4[(size_t)k * 1024 + j], W1[j * 64 + n], a);
    BWt[(size_t)n * 1024 + k] = f2bf(a);
}

// ---------------------------------------------------------------------------
// Branch GEMM: 64(M)x128(N) tile, grid (N/128, M/64) -> 256 blocks.
// C = tanh(A @ Bt^T + bias), bf16 out.  4 waves (2x2), wave = 32x64, BK=32.
// ---------------------------------------------------------------------------
__global__ __launch_bounds__(256, 2)
void gemm_branch(const u16* __restrict__ A, int lda,
                 const u16* __restrict__ Bt, int ldb,
                 const float* __restrict__ bias,
                 u16* __restrict__ Cout, int ldc, int K)
{
    __shared__ __align__(16) u16 As[2][64 * 32];    // 4 KB each buf
    __shared__ __align__(16) u16 Bs[2][128 * 32];   // 8 KB each buf
    const int tid = threadIdx.x, lane = tid & 63, wid = tid >> 6;
    const int wr = wid >> 1, wc = wid & 1;
    const int bn = blockIdx.x * 128, bm = blockIdx.y * 64;
    const int NT = K >> 5;
    const int ck = tid & 3;
    const int arow = tid >> 2;
    const u16* aSrc = A + (size_t)(bm + arow) * lda + (ck ^ (arow & 3)) * 8;
    f32x4 acc[2][4] = {};

    auto STAGE = [&](int buf, int t) {
        const int k0 = t << 5;
        gload_lds16(aSrc + k0, (char*)As[buf] + wid * 1024);
        #pragma unroll
        for (int r = 0; r < 2; ++r) {
            const int row = (r * 256 + tid) >> 2;
            gload_lds16(Bt + (size_t)(bn + row) * ldb + k0 + (ck ^ (row & 3)) * 8,
                        (char*)Bs[buf] + r * 4096 + wid * 1024);
        }
    };
    auto COMPUTE = [&](int buf) {
        s16x8 a[2], b[4];
        #pragma unroll
        for (int mi = 0; mi < 2; ++mi) {
            int row = wr * 32 + mi * 16 + (lane & 15);
            int s = (lane >> 4) ^ (row & 3);
            a[mi] = *(const s16x8*)&As[buf][row * 32 + s * 8];
        }
        #pragma unroll
        for (int ni = 0; ni < 4; ++ni) {
            int n = wc * 64 + ni * 16 + (lane & 15);
            int s = (lane >> 4) ^ (n & 3);
            b[ni] = *(const s16x8*)&Bs[buf][n * 32 + s * 8];
        }
        #pragma unroll
        for (int mi = 0; mi < 2; ++mi)
        #pragma unroll
        for (int ni = 0; ni < 4; ++ni)
            acc[mi][ni] = MFMA(a[mi], b[ni], acc[mi][ni]);
    };

    STAGE(0, 0);
    __syncthreads();
    for (int t = 0; t < NT; ++t) {
        if (t + 1 < NT) STAGE((t + 1) & 1, t + 1);
        COMPUTE(t & 1);
        __syncthreads();
    }

    #pragma unroll
    for (int mi = 0; mi < 2; ++mi)
    #pragma unroll
    for (int ni = 0; ni < 4; ++ni) {
        const int col = bn + wc * 64 + ni * 16 + (lane & 15);
        const float bv = bias[col];
        #pragma unroll
        for (int jj = 0; jj < 4; ++jj) {
            const int row = bm + wr * 32 + mi * 16 + (lane >> 4) * 4 + jj;
            Cout[(size_t)row * ldc + col] = f2bf(fast_tanh(acc[mi][ni][jj] + bv));
        }
    }
}

// ---------------------------------------------------------------------------
// z-GEMM: zc[kz][2048][64] = actB @ BWt^T partials, SK=8, 64x64 tile
// ---------------------------------------------------------------------------
__global__ __launch_bounds__(256, 2)
void zgemm(const u16* __restrict__ A, const u16* __restrict__ Bt,
           float* __restrict__ zc)
{
    __shared__ __align__(16) u16 As[2][64 * 32];
    __shared__ __align__(16) u16 Bs[2][64 * 32];
    const int tid = threadIdx.x, lane = tid & 63, wid = tid >> 6;
    const int wr = wid >> 1, wc = wid & 1;
    const int bm = blockIdx.y * 64, kz = blockIdx.z;
    const int t0 = kz * 4, nt = 4;
    const int arow = tid >> 2, ck = tid & 3;
    const u16* aSrc = A + (size_t)(bm + arow) * 1024 + (ck ^ (arow & 3)) * 8;
    const u16* bSrc = Bt + (size_t)arow * 1024 + (ck ^ (arow & 3)) * 8;
    f32x4 acc[2][2] = {};

    auto STAGE = [&](int buf, int t) {
        const int k0 = t << 5;
        gload_lds16(aSrc + k0, (char*)As[buf] + wid * 1024);
        gload_lds16(bSrc + k0, (char*)Bs[buf] + wid * 1024);
    };
    auto COMPUTE = [&](int buf) {
        s16x8 a[2];
        #pragma unroll
        for (int mi = 0; mi < 2; ++mi) {
            int row = wr * 32 + mi * 16 + (lane & 15);
            int s = (lane >> 4) ^ (row & 3);
            a[mi] = *(const s16x8*)&As[buf][row * 32 + s * 8];
        }
        #pragma unroll
        for (int ni = 0; ni < 2; ++ni) {
            int n = wc * 32 + ni * 16 + (lane & 15);
            int s = (lane >> 4) ^ (n & 3);
            s16x8 b = *(const s16x8*)&Bs[buf][n * 32 + s * 8];
            #pragma unroll
            for (int mi = 0; mi < 2; ++mi)
                acc[mi][ni] = MFMA(a[mi], b, acc[mi][ni]);
        }
    };

    STAGE(0, t0);
    __syncthreads();
    for (int t = 0; t < nt; ++t) {
        if (t + 1 < nt) STAGE((t + 1) & 1, t0 + t + 1);
        COMPUTE(t & 1);
        __syncthreads();
    }
    #pragma unroll
    for (int mi = 0; mi < 2; ++mi)
    #pragma unroll
    for (int ni = 0; ni < 2; ++ni) {
        const int col = wc * 32 + ni * 16 + (lane & 15);
        #pragma unroll
        for (int jj = 0; jj < 4; ++jj) {
            const int row = bm + wr * 32 + mi * 16 + (lane >> 4) * 4 + jj;
            zc[((size_t)kz * 2048 + row) * 64 + col] = acc[mi][ni][jj];
        }
    }
}

// ---------------------------------------------------------------------------
// Fused: reduce_z (+bz) -> z bf16 ; trunk L1 (K=64, VALU) -> h1 bf16
// block = 32 rows; 256 threads: o = tid&127, row-half = tid>>7
// ---------------------------------------------------------------------------
__global__ __launch_bounds__(256)
void z_l1_h1(const float* __restrict__ zc, const float* __restrict__ bz,
             const float* __restrict__ W2, const float* __restrict__ t,
             u16* __restrict__ z, u16* __restrict__ h1)
{
    __shared__ float zsh[32][64];
    const int rb = blockIdx.x * 32;
    #pragma unroll
    for (int ii = 0; ii < 8; ++ii) {
        int e = ii * 256 + threadIdx.x;          // e = r*64 + k
        int r = e >> 6, k = e & 63;
        size_t off = (size_t)(rb + r) * 64 + k;
        float s = bz[k];
        #pragma unroll
        for (int sk = 0; sk < 8; ++sk) s += zc[(size_t)sk * 2048 * 64 + off];
        zsh[r][k] = s;
        z[off] = f2bf(s);
    }
    __syncthreads();
    const int o = threadIdx.x & 127;
    const int rh = (threadIdx.x >> 7) * 16;
    float acc_a[16] = {}, acc_b[16] = {};
    for (int k = 0; k < 64; ++k) {
        float wa = W2[(size_t)k * LDP + o];
        float wb = W2[(size_t)k * LDP + 128 + o];
        #pragma unroll
        for (int r = 0; r < 16; ++r) {
            float zv = zsh[rh + r][k];
            acc_a[r] = fmaf(zv, wa, acc_a[r]);
            acc_b[r] = fmaf(zv, wb, acc_b[r]);
        }
    }
    #pragma unroll
    for (int r = 0; r < 16; ++r) {
        int b = rb + rh + r;
        h1[b * 128 + o] = f2bf(fast_tanh(t[b] * acc_b[r] + acc_a[r]));
    }
}

// ---------------------------------------------------------------------------
// Trunk GEMM: Cp[kz][2048][128] partials; A generated on the fly (bf16):
//   p<8192: h[b,p>>6]*z[b,p&63] ; else z[b,p-8192].  K=8256, SK=16.
// ---------------------------------------------------------------------------
__global__ __launch_bounds__(256, 2)
void trunk128(const u16* __restrict__ h, const u16* __restrict__ z,
              const u16* __restrict__ Bt, float* __restrict__ Cp)
{
    constexpr int NT = 258, SKT = 16;
    __shared__ __align__(16) u16 As[2][128 * 32];
    __shared__ __align__(16) u16 Bs[2][128 * 32];
    const int tid = threadIdx.x, lane = tid & 63, wid = tid >> 6;
    const int wr = wid >> 1, wc = wid & 1;
    const int bm = blockIdx.x * 128, kz = blockIdx.y;
    const int t0 = (NT * kz) / SKT, t1 = (NT * (kz + 1)) / SKT;
    const int ck = tid & 3;
    const int arow = tid >> 1;
    const int b = bm + arow;
    const int c0 = (tid & 1) * 2, c1 = c0 + 1;
    const s16x8 zA0 = *(const s16x8*)&z[b * 64 + c0 * 8];
    const s16x8 zA1 = *(const s16x8*)&z[b * 64 + c1 * 8];
    const s16x8 zB0 = *(const s16x8*)&z[b * 64 + 32 + c0 * 8];
    const s16x8 zB1 = *(const s16x8*)&z[b * 64 + 32 + c1 * 8];
    const int s0 = (c0 ^ (arow & 3)) * 8, s1 = (c1 ^ (arow & 3)) * 8;
    f32x4 acc[4][4] = {};

    auto STAGE = [&](int buf, int t) {
        const int p0 = t << 5;
        #pragma unroll
        for (int r = 0; r < 2; ++r) {
            const int n = (r * 256 + tid) >> 2;
            gload_lds16(Bt + (size_t)n * 8256 + p0 + (ck ^ (n & 3)) * 8,
                        (char*)Bs[buf] + r * 4096 + wid * 1024);
        }
        const s16x8 za = (p0 & 32) ? zB0 : zA0;
        const s16x8 zb = (p0 & 32) ? zB1 : zA1;
        u16 o0[8], o1[8];
        if (p0 < 8192) {
            const float hf = bf2f(h[b * 128 + (p0 >> 6)]);
            #pragma unroll
            for (int j = 0; j < 8; ++j) {
                o0[j] = f2bf(hf * bf2f((u16)za[j]));
                o1[j] = f2bf(hf * bf2f((u16)zb[j]));
            }
        } else {
            #pragma unroll
            for (int j = 0; j < 8; ++j) { o0[j] = (u16)za[j]; o1[j] = (u16)zb[j]; }
        }
        *(s16x8*)&As[buf][arow * 32 + s0] = *(s16x8*)o0;
        *(s16x8*)&As[buf][arow * 32 + s1] = *(s16x8*)o1;
    };
    auto COMPUTE = [&](int buf) {
        s16x8 a[4], bb[4];
        #pragma unroll
        for (int mi = 0; mi < 4; ++mi) {
            int row = wr * 64 + mi * 16 + (lane & 15);
            int s = (lane >> 4) ^ (row & 3);
            a[mi] = *(const s16x8*)&As[buf][row * 32 + s * 8];
        }
        #pragma unroll
        for (int ni = 0; ni < 4; ++ni) {
            int n = wc * 64 + ni * 16 + (lane & 15);
            int s = (lane >> 4) ^ (n & 3);
            bb[ni] = *(const s16x8*)&Bs[buf][n * 32 + s * 8];
        }
        #pragma unroll
        for (int mi = 0; mi < 4; ++mi)
        #pragma unroll
        for (int ni = 0; ni < 4; ++ni)
            acc[mi][ni] = MFMA(a[mi], bb[ni], acc[mi][ni]);
    };

    STAGE(0, t0);
    __syncthreads();
    const int nt = t1 - t0;
    for (int t = 0; t < nt; ++t) {
        if (t + 1 < nt) STAGE((t + 1) & 1, t0 + t + 1);
        COMPUTE(t & 1);
        __syncthreads();
    }

    #pragma unroll
    for (int mi = 0; mi < 4; ++mi)
    #pragma unroll
    for (int ni = 0; ni < 4; ++ni) {
        const int col = wc * 64 + ni * 16 + (lane & 15);
        #pragma unroll
        for (int jj = 0; jj < 4; ++jj) {
            const int row = bm + wr * 64 + mi * 16 + (lane >> 4) * 4 + jj;
            Cp[((size_t)kz * 2048 + row) * 128 + col] = acc[mi][ni][jj];
        }
    }
}

// ---------------------------------------------------------------------------
__global__ __launch_bounds__(256)
void reduce_tanh(const float* __restrict__ Cp, u16* __restrict__ hout) {
    const int idx = blockIdx.x * 256 + threadIdx.x;      // 2048*128
    const size_t S = (size_t)2048 * 128;
    float s = 0.f;
    #pragma unroll
    for (int k = 0; k < 16; ++k) s += Cp[idx + k * S];
    hout[idx] = f2bf(fast_tanh(s));
}

// layer-3 reduce+tanh fused with trunk L4 + final combine
__global__ __launch_bounds__(256)
void reduce_out(const float* __restrict__ Cp, const u16* __restrict__ z,
                const float* __restrict__ W2, const float* __restrict__ t,
                const float* __restrict__ u, float* __restrict__ out)
{
    __shared__ float sh[4][128];
    const int wv = threadIdx.x >> 6, l = threadIdx.x & 63;
    const int b = blockIdx.x * 4 + wv;
    const size_t S = (size_t)2048 * 128;
    #pragma unroll
    for (int e = l; e < 128; e += 64) {
        float s = 0.f;
        #pragma unroll
        for (int k = 0; k < 16; ++k) s += Cp[k * S + (size_t)b * 128 + e];
        sh[wv][e] = fast_tanh(s);
    }
    __syncthreads();
    const float* wrow = &W2[(size_t)l * LDP + 33280];
    float acc = wrow[0];
    #pragma unroll 8
    for (int i = 0; i < 128; ++i) acc = fmaf(sh[wv][i], wrow[1 + i], acc);
    float p = bf2f(z[b * 64 + l]) * acc;
    #pragma unroll
    for (int off = 32; off > 0; off >>= 1) p += __shfl_down(p, off);
    if (l == 0) out[b] = u[b * 128] + t[b] * p;
}

// ---------------------------------------------------------------------------
extern "C" void kernel_launch(void* const* d_in, const int* in_sizes, int n_in,
                              void* d_out, int out_size, void* d_ws, size_t ws_size,
                              hipStream_t stream)
{
    const float* t   = (const float*)d_in[0];
    const float* u   = (const float*)d_in[1];
    const float* bw0 = (const float*)d_in[2];
    const float* bb0 = (const float*)d_in[3];
    const float* bw1 = (const float*)d_in[4];
    const float* bb1 = (const float*)d_in[5];
    const float* bw2 = (const float*)d_in[6];
    const float* bb2 = (const float*)d_in[7];
    const float* bw3 = (const float*)d_in[8];
    const float* bb3 = (const float*)d_in[9];
    const float* bw4 = (const float*)d_in[10];
    const float* bb4 = (const float*)d_in[11];
    const float* W1  = (const float*)d_in[12];
    const float* W2  = (const float*)d_in[13];
    float* out = (float*)d_out;

    // ---- workspace layout (bytes)
    char* base = (char*)d_ws;
    u16*   bw1t = (u16*)(base);                  // 2 MB
    u16*   bw2t = (u16*)(base + 2097152);        // 2 MB
    u16*   bw3t = (u16*)(base + 4194304);        // 2 MB
    u16*   actA = (u16*)(base + 6291456);        // 4 MB
    u16*   actB = (u16*)(base + 10485760);       // 4 MB
    u16*   ubf  = (u16*)(base + 14680064);       // 512 KB
    u16*   bw0t = (u16*)(base + 15204352);       // 256 KB
    u16*   BWt  = (u16*)(base + 15499264);       // 128 KB
    float* bz   = (float*)(base + 15630336);     // 256 B
    // [everything above dead before trunk L2 -> Cp overlays it]
    u16*   z    = (u16*)(base + 16777216);       // 256 KB
    u16*   h1   = (u16*)(base + 17039360);       // 512 KB
    u16*   h2   = (u16*)(base + 17563648);       // 512 KB
    u16*   Bt   = (u16*)(base + 18087936);       // 4,227,072 (2 layers)
    // overlays:
    float* zc = (float*)(base);                  // 4 MB   (zgemm .. z_l1_h1)
    float* Cp = (float*)(base);                  // 16.78 MB (trunk partials)

    dim3 blk(256);
    // ---- prep (6 dispatches)
    cvt_plain<<<128, blk, 0, stream>>>(u, ubf, 2048 * 128);
    transpose_cvt<<<dim3(16, 2), blk, 0, stream>>>(bw0, 1024, bw0t, 128);
    transpose3<<<dim3(16, 16, 3), blk, 0, stream>>>(bw1, bw2, bw3, bw1t, bw2t, bw3t);
    bw_bz<<<257, blk, 0, stream>>>(bw4, W1, bb4, BWt, bz);
    gather_trunk<<<dim3(129, 2), blk, 0, stream>>>(W2, Bt);

    // ---- branch MLP, 64x128 tiles, 256 blocks each
    gemm_branch<<<dim3(8, 32), blk, 0, stream>>>(ubf,  128,  bw0t, 128,  bb0, actA, 1024, 128);
    gemm_branch<<<dim3(8, 32), blk, 0, stream>>>(actA, 1024, bw1t, 1024, bb1, actB, 1024, 1024);
    gemm_branch<<<dim3(8, 32), blk, 0, stream>>>(actB, 1024, bw2t, 1024, bb2, actA, 1024, 1024);
    gemm_branch<<<dim3(8, 32), blk, 0, stream>>>(actA, 1024, bw3t, 1024, bb3, actB, 1024, 1024);
    // ---- z partials (SK=8, 256 blocks)
    zgemm<<<dim3(1, 32, 8), blk, 0, stream>>>(actB, BWt, zc);
    // ---- fused reduce_z + trunk L1 + h1
    z_l1_h1<<<64, blk, 0, stream>>>(zc, bz, W2, t, z, h1);
    // ---- trunk layers 2,3 (128x128 tiles, split-K=16)
    trunk128<<<dim3(16, 16), blk, 0, stream>>>(h1, z, Bt, Cp);
    reduce_tanh<<<1024, blk, 0, stream>>>(Cp, h2);
    trunk128<<<dim3(16, 16), blk, 0, stream>>>(h2, z, Bt + (size_t)128 * 8256, Cp);
    // ---- layer-3 reduce + trunk L4 + combine
    reduce_out<<<512, blk, 0, stream>>>(Cp, z, W2, t, u, out);
}

// Round 8
// 159.112 us; speedup vs baseline: 4.7090x; 1.1814x over previous
//
#include <hip/hip_runtime.h>
#include <hip/hip_bf16.h>
#include <stdint.h>

typedef unsigned short u16;
typedef unsigned int   u32;
typedef short s16x8 __attribute__((ext_vector_type(8)));
typedef float f32x4 __attribute__((ext_vector_type(4)));

#define LDP 33409

__device__ __forceinline__ u16 f2bf(float f) {
    union { float f; u32 u; } v; v.f = f;
    u32 r = v.u + 0x7fffu + ((v.u >> 16) & 1u);
    return (u16)(r >> 16);
}
__device__ __forceinline__ float bf2f(u16 h) {
    union { u32 u; float f; } v; v.u = ((u32)h) << 16;
    return v.f;
}
__device__ __forceinline__ float fast_tanh(float x) {
    float e = __expf(2.0f * x);
    return 1.0f - 2.0f / (e + 1.0f);
}
__device__ __forceinline__ f32x4 MFMA(s16x8 a, s16x8 b, f32x4 c) {
    return __builtin_amdgcn_mfma_f32_16x16x32_bf16(a, b, c, 0, 0, 0);
}
__device__ __forceinline__ void gload_lds16(const void* g, void* l) {
    __builtin_amdgcn_global_load_lds(
        (const __attribute__((address_space(1))) u32*)(uintptr_t)g,
        (__attribute__((address_space(3))) u32*)(uintptr_t)l, 16, 0, 0);
}

// ---------------------------------------------------------------------------
// MEGA-PREP: one dispatch, 1443 blocks.
//   [0,128)      cvt u -> ubf (bf16)
//   [128,160)    transpose bw0 [128,1024] -> bw0t[1024][128]
//   [160,928)    transpose bw1/bw2/bw3 -> bwXt[1024][1024]  (3 x 256)
//   [928,1185)   BWt[n][k] = (bw4@W1)[k][n] exact f32; block 1184: bz
//   [1185,1443)  gather trunk Bt[layer][n][p]  (2 x 129)
// ---------------------------------------------------------------------------
__global__ __launch_bounds__(256)
void prep_all(const float* __restrict__ u,
              const float* __restrict__ bw0, const float* __restrict__ bw1,
              const float* __restrict__ bw2, const float* __restrict__ bw3,
              const float* __restrict__ bw4, const float* __restrict__ bb4,
              const float* __restrict__ W1,  const float* __restrict__ W2,
              u16* __restrict__ ubf, u16* __restrict__ bw0t,
              u16* __restrict__ bw1t, u16* __restrict__ bw2t,
              u16* __restrict__ bw3t, u16* __restrict__ BWt,
              float* __restrict__ bz, u16* __restrict__ Btb)
{
    __shared__ __align__(16) char ldsbuf[33280];
    const int bid = blockIdx.x, tid = threadIdx.x;

    if (bid < 128) {                       // ---- u -> bf16
        int i = (bid * 256 + tid) * 8;
        float4 a = *(const float4*)&u[i];
        float4 b = *(const float4*)&u[i + 4];
        uint4 o;
        o.x = (u32)f2bf(a.x) | ((u32)f2bf(a.y) << 16);
        o.y = (u32)f2bf(a.z) | ((u32)f2bf(a.w) << 16);
        o.z = (u32)f2bf(b.x) | ((u32)f2bf(b.y) << 16);
        o.w = (u32)f2bf(b.z) | ((u32)f2bf(b.w) << 16);
        *(uint4*)&ubf[i] = o;
    } else if (bid < 928) {                // ---- transposes
        float (*tile)[65] = (float(*)[65])ldsbuf;
        const float* src; u16* dst; int ldsrc, lddst, rb, cb;
        if (bid < 160) {
            int idx = bid - 128;           // (16 x 2): x over 1024 cols, y over 128 rows
            src = bw0; dst = bw0t; ldsrc = 1024; lddst = 128;
            rb = (idx >> 4) * 64; cb = (idx & 15) * 64;
        } else {
            int idx = bid - 160;
            int layer = idx >> 8, w = idx & 255;
            src = layer == 0 ? bw1 : (layer == 1 ? bw2 : bw3);
            dst = layer == 0 ? bw1t : (layer == 1 ? bw2t : bw3t);
            ldsrc = 1024; lddst = 1024;
            rb = (w >> 4) * 64; cb = (w & 15) * 64;
        }
        for (int i = tid; i < 64 * 64; i += 256) {
            int r = i >> 6, c = i & 63;
            tile[r][c] = src[(size_t)(rb + r) * ldsrc + cb + c];
        }
        __syncthreads();
        for (int i = tid; i < 64 * 64; i += 256) {
            int c = i >> 6, r = i & 63;
            dst[(size_t)(cb + c) * lddst + rb + r] = f2bf(tile[r][c]);
        }
    } else if (bid < 1185) {               // ---- BWt / bz (exact f32)
        int lb = bid - 928;
        if (lb == 256) {
            if (tid < 64) {
                float a = 0.f;
                for (int j = 0; j < 1024; ++j) a = fmaf(bb4[j], W1[j * 64 + tid], a);
                bz[tid] = a;
            }
            return;
        }
        const int n = tid & 63;
        const int k = lb * 4 + (tid >> 6);
        float a = 0.f;
        for (int j = 0; j < 1024; ++j) a = fmaf(bw4[(size_t)k * 1024 + j], W1[j * 64 + n], a);
        BWt[(size_t)n * 1024 + k] = f2bf(a);
    } else {                               // ---- gather trunk weights
        float (*tile)[130] = (float(*)[130])ldsbuf;
        int idx = bid - 1185;
        int layer = idx / 129, pbi = idx % 129;
        u16* Bt = Btb + (size_t)layer * 128 * 8256;
        const int colbase = layer ? 16896 : 384, biasbase = layer ? 16768 : 256;
        const int pb = pbi * 64;
        for (int i = tid; i < 64 * 128; i += 256) {
            int p = pb + (i >> 7), n = i & 127;
            float v = (p < 8192)
                ? W2[(size_t)(p & 63) * LDP + colbase + (size_t)(p >> 6) * 128 + n]
                : W2[(size_t)(p - 8192) * LDP + biasbase + n];
            tile[i >> 7][n] = v;
        }
        __syncthreads();
        for (int i = tid; i < 64 * 128; i += 256) {
            int n = i >> 6, dp = i & 63;
            Bt[(size_t)n * 8256 + pb + dp] = f2bf(tile[dp][n]);
        }
    }
}

// ---------------------------------------------------------------------------
// Branch GEMM: 64x64 tile, grid (16,32) = 512 blocks -> 2 blocks/CU.
// C = tanh(A @ Bt^T + bias), bf16 out. 4 waves (2x2), wave 32x32, BK=32.
// ---------------------------------------------------------------------------
__global__ __launch_bounds__(256, 2)
void gemm_branch(const u16* __restrict__ A, int lda,
                 const u16* __restrict__ Bt, int ldb,
                 const float* __restrict__ bias,
                 u16* __restrict__ Cout, int ldc, int K)
{
    __shared__ __align__(16) u16 As[2][64 * 32];
    __shared__ __align__(16) u16 Bs[2][64 * 32];
    const int tid = threadIdx.x, lane = tid & 63, wid = tid >> 6;
    const int wr = wid >> 1, wc = wid & 1;
    const int bn = blockIdx.x * 64, bm = blockIdx.y * 64;
    const int NT = K >> 5;
    const int arow = tid >> 2, ck = tid & 3;
    const u16* aSrc = A + (size_t)(bm + arow) * lda + (ck ^ (arow & 3)) * 8;
    const u16* bSrc = Bt + (size_t)(bn + arow) * ldb + (ck ^ (arow & 3)) * 8;
    f32x4 acc[2][2] = {};

    auto STAGE = [&](int buf, int t) {
        const int k0 = t << 5;
        gload_lds16(aSrc + k0, (char*)As[buf] + wid * 1024);
        gload_lds16(bSrc + k0, (char*)Bs[buf] + wid * 1024);
    };
    auto COMPUTE = [&](int buf) {
        s16x8 a[2], b[2];
        #pragma unroll
        for (int mi = 0; mi < 2; ++mi) {
            int row = wr * 32 + mi * 16 + (lane & 15);
            int s = (lane >> 4) ^ (row & 3);
            a[mi] = *(const s16x8*)&As[buf][row * 32 + s * 8];
        }
        #pragma unroll
        for (int ni = 0; ni < 2; ++ni) {
            int n = wc * 32 + ni * 16 + (lane & 15);
            int s = (lane >> 4) ^ (n & 3);
            b[ni] = *(const s16x8*)&Bs[buf][n * 32 + s * 8];
        }
        #pragma unroll
        for (int mi = 0; mi < 2; ++mi)
        #pragma unroll
        for (int ni = 0; ni < 2; ++ni)
            acc[mi][ni] = MFMA(a[mi], b[ni], acc[mi][ni]);
    };

    STAGE(0, 0);
    __syncthreads();
    for (int t = 0; t < NT; ++t) {
        if (t + 1 < NT) STAGE((t + 1) & 1, t + 1);
        COMPUTE(t & 1);
        __syncthreads();
    }

    #pragma unroll
    for (int mi = 0; mi < 2; ++mi)
    #pragma unroll
    for (int ni = 0; ni < 2; ++ni) {
        const int col = bn + wc * 32 + ni * 16 + (lane & 15);
        const float bv = bias[col];
        #pragma unroll
        for (int jj = 0; jj < 4; ++jj) {
            const int row = bm + wr * 32 + mi * 16 + (lane >> 4) * 4 + jj;
            Cout[(size_t)row * ldc + col] = f2bf(fast_tanh(acc[mi][ni][jj] + bv));
        }
    }
}

// ---------------------------------------------------------------------------
// z-GEMM: zc[kz][2048][64] = actB @ BWt^T partials, SK=8, 64x64 tile
// ---------------------------------------------------------------------------
__global__ __launch_bounds__(256, 2)
void zgemm(const u16* __restrict__ A, const u16* __restrict__ Bt,
           float* __restrict__ zc)
{
    __shared__ __align__(16) u16 As[2][64 * 32];
    __shared__ __align__(16) u16 Bs[2][64 * 32];
    const int tid = threadIdx.x, lane = tid & 63, wid = tid >> 6;
    const int wr = wid >> 1, wc = wid & 1;
    const int bm = blockIdx.y * 64, kz = blockIdx.z;
    const int t0 = kz * 4, nt = 4;
    const int arow = tid >> 2, ck = tid & 3;
    const u16* aSrc = A + (size_t)(bm + arow) * 1024 + (ck ^ (arow & 3)) * 8;
    const u16* bSrc = Bt + (size_t)arow * 1024 + (ck ^ (arow & 3)) * 8;
    f32x4 acc[2][2] = {};

    auto STAGE = [&](int buf, int t) {
        const int k0 = t << 5;
        gload_lds16(aSrc + k0, (char*)As[buf] + wid * 1024);
        gload_lds16(bSrc + k0, (char*)Bs[buf] + wid * 1024);
    };
    auto COMPUTE = [&](int buf) {
        s16x8 a[2];
        #pragma unroll
        for (int mi = 0; mi < 2; ++mi) {
            int row = wr * 32 + mi * 16 + (lane & 15);
            int s = (lane >> 4) ^ (row & 3);
            a[mi] = *(const s16x8*)&As[buf][row * 32 + s * 8];
        }
        #pragma unroll
        for (int ni = 0; ni < 2; ++ni) {
            int n = wc * 32 + ni * 16 + (lane & 15);
            int s = (lane >> 4) ^ (n & 3);
            s16x8 b = *(const s16x8*)&Bs[buf][n * 32 + s * 8];
            #pragma unroll
            for (int mi = 0; mi < 2; ++mi)
                acc[mi][ni] = MFMA(a[mi], b, acc[mi][ni]);
        }
    };

    STAGE(0, t0);
    __syncthreads();
    for (int t = 0; t < nt; ++t) {
        if (t + 1 < nt) STAGE((t + 1) & 1, t0 + t + 1);
        COMPUTE(t & 1);
        __syncthreads();
    }
    #pragma unroll
    for (int mi = 0; mi < 2; ++mi)
    #pragma unroll
    for (int ni = 0; ni < 2; ++ni) {
        const int col = wc * 32 + ni * 16 + (lane & 15);
        #pragma unroll
        for (int jj = 0; jj < 4; ++jj) {
            const int row = bm + wr * 32 + mi * 16 + (lane >> 4) * 4 + jj;
            zc[((size_t)kz * 2048 + row) * 64 + col] = acc[mi][ni][jj];
        }
    }
}

// ---------------------------------------------------------------------------
// Fused: reduce_z (+bz) -> z bf16 ; trunk L1 (K=64, VALU) -> h1 bf16
// ---------------------------------------------------------------------------
__global__ __launch_bounds__(256)
void z_l1_h1(const float* __restrict__ zc, const float* __restrict__ bz,
             const float* __restrict__ W2, const float* __restrict__ t,
             u16* __restrict__ z, u16* __restrict__ h1)
{
    __shared__ float zsh[32][64];
    const int rb = blockIdx.x * 32;
    #pragma unroll
    for (int ii = 0; ii < 8; ++ii) {
        int e = ii * 256 + threadIdx.x;
        int r = e >> 6, k = e & 63;
        size_t off = (size_t)(rb + r) * 64 + k;
        float s = bz[k];
        #pragma unroll
        for (int sk = 0; sk < 8; ++sk) s += zc[(size_t)sk * 2048 * 64 + off];
        zsh[r][k] = s;
        z[off] = f2bf(s);
    }
    __syncthreads();
    const int o = threadIdx.x & 127;
    const int rh = (threadIdx.x >> 7) * 16;
    float acc_a[16] = {}, acc_b[16] = {};
    for (int k = 0; k < 64; ++k) {
        float wa = W2[(size_t)k * LDP + o];
        float wb = W2[(size_t)k * LDP + 128 + o];
        #pragma unroll
        for (int r = 0; r < 16; ++r) {
            float zv = zsh[rh + r][k];
            acc_a[r] = fmaf(zv, wa, acc_a[r]);
            acc_b[r] = fmaf(zv, wb, acc_b[r]);
        }
    }
    #pragma unroll
    for (int r = 0; r < 16; ++r) {
        int b = rb + rh + r;
        h1[b * 128 + o] = f2bf(fast_tanh(t[b] * acc_b[r] + acc_a[r]));
    }
}

// ---------------------------------------------------------------------------
// Trunk GEMM: 512 threads / 8 waves (4Mx2N), 128x128 tile, SK=16.
// A generated on the fly: p<8192: h[b,p>>6]*z[b,p&63]; else z[b,p-8192].
// ---------------------------------------------------------------------------
__global__ __launch_bounds__(512, 2)
void trunk128(const u16* __restrict__ h, const u16* __restrict__ z,
              const u16* __restrict__ Bt, float* __restrict__ Cp)
{
    constexpr int NT = 258, SKT = 16;
    __shared__ __align__(16) u16 As[2][128 * 32];
    __shared__ __align__(16) u16 Bs[2][128 * 32];
    const int tid = threadIdx.x, lane = tid & 63, wid = tid >> 6;
    const int wr = wid >> 1, wc = wid & 1;          // 4 M-waves x 2 N-waves
    const int bm = blockIdx.x * 128, kz = blockIdx.y;
    const int t0 = (NT * kz) / SKT, t1 = (NT * (kz + 1)) / SKT;
    const int arow = tid >> 2, ck = tid & 3;        // 128 rows x 4 chunks
    const int b = bm + arow;
    const s16x8 zlo = *(const s16x8*)&z[b * 64 + ck * 8];
    const s16x8 zhi = *(const s16x8*)&z[b * 64 + 32 + ck * 8];
    const int slot = (ck ^ (arow & 3)) * 8;
    f32x4 acc[2][4] = {};

    auto STAGE = [&](int buf, int t) {
        const int p0 = t << 5;
        gload_lds16(Bt + (size_t)arow * 8256 + p0 + (ck ^ (arow & 3)) * 8,
                    (char*)Bs[buf] + wid * 1024);
        const s16x8 zv = (p0 & 32) ? zhi : zlo;
        u16 o8[8];
        if (p0 < 8192) {
            const float hf = bf2f(h[b * 128 + (p0 >> 6)]);
            #pragma unroll
            for (int j = 0; j < 8; ++j) o8[j] = f2bf(hf * bf2f((u16)zv[j]));
        } else {
            #pragma unroll
            for (int j = 0; j < 8; ++j) o8[j] = (u16)zv[j];
        }
        *(s16x8*)&As[buf][arow * 32 + slot] = *(s16x8*)o8;
    };
    auto COMPUTE = [&](int buf) {
        s16x8 a[2], bb[4];
        #pragma unroll
        for (int mi = 0; mi < 2; ++mi) {
            int row = wr * 32 + mi * 16 + (lane & 15);
            int s = (lane >> 4) ^ (row & 3);
            a[mi] = *(const s16x8*)&As[buf][row * 32 + s * 8];
        }
        #pragma unroll
        for (int ni = 0; ni < 4; ++ni) {
            int n = wc * 64 + ni * 16 + (lane & 15);
            int s = (lane >> 4) ^ (n & 3);
            bb[ni] = *(const s16x8*)&Bs[buf][n * 32 + s * 8];
        }
        #pragma unroll
        for (int mi = 0; mi < 2; ++mi)
        #pragma unroll
        for (int ni = 0; ni < 4; ++ni)
            acc[mi][ni] = MFMA(a[mi], bb[ni], acc[mi][ni]);
    };

    STAGE(0, t0);
    __syncthreads();
    const int nt = t1 - t0;
    for (int t = 0; t < nt; ++t) {
        if (t + 1 < nt) STAGE((t + 1) & 1, t0 + t + 1);
        COMPUTE(t & 1);
        __syncthreads();
    }

    #pragma unroll
    for (int mi = 0; mi < 2; ++mi)
    #pragma unroll
    for (int ni = 0; ni < 4; ++ni) {
        const int col = wc * 64 + ni * 16 + (lane & 15);
        #pragma unroll
        for (int jj = 0; jj < 4; ++jj) {
            const int row = bm + wr * 32 + mi * 16 + (lane >> 4) * 4 + jj;
            Cp[((size_t)kz * 2048 + row) * 128 + col] = acc[mi][ni][jj];
        }
    }
}

// ---------------------------------------------------------------------------
__global__ __launch_bounds__(256)
void reduce_tanh(const float* __restrict__ Cp, u16* __restrict__ hout) {
    const int idx = blockIdx.x * 256 + threadIdx.x;
    const size_t S = (size_t)2048 * 128;
    float s = 0.f;
    #pragma unroll
    for (int k = 0; k < 16; ++k) s += Cp[idx + k * S];
    hout[idx] = f2bf(fast_tanh(s));
}

// layer-3 reduce+tanh fused with trunk L4 + final combine
__global__ __launch_bounds__(256)
void reduce_out(const float* __restrict__ Cp, const u16* __restrict__ z,
                const float* __restrict__ W2, const float* __restrict__ t,
                const float* __restrict__ u, float* __restrict__ out)
{
    __shared__ float sh[4][128];
    const int wv = threadIdx.x >> 6, l = threadIdx.x & 63;
    const int b = blockIdx.x * 4 + wv;
    const size_t S = (size_t)2048 * 128;
    #pragma unroll
    for (int e = l; e < 128; e += 64) {
        float s = 0.f;
        #pragma unroll
        for (int k = 0; k < 16; ++k) s += Cp[k * S + (size_t)b * 128 + e];
        sh[wv][e] = fast_tanh(s);
    }
    __syncthreads();
    const float* wrow = &W2[(size_t)l * LDP + 33280];
    float acc = wrow[0];
    #pragma unroll 8
    for (int i = 0; i < 128; ++i) acc = fmaf(sh[wv][i], wrow[1 + i], acc);
    float p = bf2f(z[b * 64 + l]) * acc;
    #pragma unroll
    for (int off = 32; off > 0; off >>= 1) p += __shfl_down(p, off);
    if (l == 0) out[b] = u[b * 128] + t[b] * p;
}

// ---------------------------------------------------------------------------
extern "C" void kernel_launch(void* const* d_in, const int* in_sizes, int n_in,
                              void* d_out, int out_size, void* d_ws, size_t ws_size,
                              hipStream_t stream)
{
    const float* t   = (const float*)d_in[0];
    const float* u   = (const float*)d_in[1];
    const float* bw0 = (const float*)d_in[2];
    const float* bb0 = (const float*)d_in[3];
    const float* bw1 = (const float*)d_in[4];
    const float* bb1 = (const float*)d_in[5];
    const float* bw2 = (const float*)d_in[6];
    const float* bb2 = (const float*)d_in[7];
    const float* bw3 = (const float*)d_in[8];
    const float* bb3 = (const float*)d_in[9];
    const float* bw4 = (const float*)d_in[10];
    const float* bb4 = (const float*)d_in[11];
    const float* W1  = (const float*)d_in[12];
    const float* W2  = (const float*)d_in[13];
    float* out = (float*)d_out;

    // ---- workspace layout (bytes)
    char* base = (char*)d_ws;
    u16*   bw1t = (u16*)(base);                  // 2 MB
    u16*   bw2t = (u16*)(base + 2097152);        // 2 MB
    u16*   bw3t = (u16*)(base + 4194304);        // 2 MB
    u16*   actA = (u16*)(base + 6291456);        // 4 MB
    u16*   actB = (u16*)(base + 10485760);       // 4 MB
    u16*   ubf  = (u16*)(base + 14680064);       // 512 KB
    u16*   bw0t = (u16*)(base + 15204352);       // 256 KB
    u16*   BWt  = (u16*)(base + 15499264);       // 128 KB
    float* bz   = (float*)(base + 15630336);     // 256 B
    u16*   z    = (u16*)(base + 16777216);       // 256 KB
    u16*   h1   = (u16*)(base + 17039360);       // 512 KB
    u16*   h2   = (u16*)(base + 17563648);       // 512 KB
    u16*   Bt   = (u16*)(base + 18087936);       // 4,227,072 (2 layers)
    // overlays:
    float* zc = (float*)(base);                  // 4 MB   (zgemm .. z_l1_h1)
    float* Cp = (float*)(base);                  // 16.78 MB (trunk partials)

    dim3 blk(256);
    // ---- prep: ONE dispatch
    prep_all<<<1443, blk, 0, stream>>>(u, bw0, bw1, bw2, bw3, bw4, bb4, W1, W2,
                                       ubf, bw0t, bw1t, bw2t, bw3t, BWt, bz, Bt);

    // ---- branch MLP, 64x64 tiles, 512 blocks (2/CU)
    gemm_branch<<<dim3(16, 32), blk, 0, stream>>>(ubf,  128,  bw0t, 128,  bb0, actA, 1024, 128);
    gemm_branch<<<dim3(16, 32), blk, 0, stream>>>(actA, 1024, bw1t, 1024, bb1, actB, 1024, 1024);
    gemm_branch<<<dim3(16, 32), blk, 0, stream>>>(actB, 1024, bw2t, 1024, bb2, actA, 1024, 1024);
    gemm_branch<<<dim3(16, 32), blk, 0, stream>>>(actA, 1024, bw3t, 1024, bb3, actB, 1024, 1024);
    // ---- z partials (SK=8)
    zgemm<<<dim3(1, 32, 8), blk, 0, stream>>>(actB, BWt, zc);
    // ---- fused reduce_z + trunk L1 + h1
    z_l1_h1<<<64, blk, 0, stream>>>(zc, bz, W2, t, z, h1);
    // ---- trunk layers 2,3 (128x128 tiles, 8 waves, split-K=16)
    trunk128<<<dim3(16, 16), dim3(512), 0, stream>>>(h1, z, Bt, Cp);
    reduce_tanh<<<1024, blk, 0, stream>>>(Cp, h2);
    trunk128<<<dim3(16, 16), dim3(512), 0, stream>>>(h2, z, Bt + (size_t)128 * 8256, Cp);
    // ---- layer-3 reduce + trunk L4 + combine
    reduce_out<<<512, blk, 0, stream>>>(Cp, z, W2, t, u, out);
}

// Round 9
// 138.486 us; speedup vs baseline: 5.4104x; 1.1489x over previous
//
#include <hip/hip_runtime.h>
#include <hip/hip_bf16.h>
#include <stdint.h>

typedef unsigned short u16;
typedef unsigned int   u32;
typedef short s16x8 __attribute__((ext_vector_type(8)));
typedef float f32x4 __attribute__((ext_vector_type(4)));

#define LDP 33409

__device__ __forceinline__ u16 f2bf(float f) {
    union { float f; u32 u; } v; v.f = f;
    u32 r = v.u + 0x7fffu + ((v.u >> 16) & 1u);
    return (u16)(r >> 16);
}
__device__ __forceinline__ float bf2f(u16 h) {
    union { u32 u; float f; } v; v.u = ((u32)h) << 16;
    return v.f;
}
__device__ __forceinline__ float fast_tanh(float x) {
    float e = __expf(2.0f * x);
    return 1.0f - 2.0f / (e + 1.0f);
}
__device__ __forceinline__ f32x4 MFMA(s16x8 a, s16x8 b, f32x4 c) {
    return __builtin_amdgcn_mfma_f32_16x16x32_bf16(a, b, c, 0, 0, 0);
}
__device__ __forceinline__ void gload_lds16(const void* g, void* l) {
    __builtin_amdgcn_global_load_lds(
        (const __attribute__((address_space(1))) u32*)(uintptr_t)g,
        (__attribute__((address_space(3))) u32*)(uintptr_t)l, 16, 0, 0);
}

// ---------------------------------------------------------------------------
// prep0: [0,128) cvt u -> ubf ; [128,160) transpose bw0 -> bw0t[1024][128]
// ---------------------------------------------------------------------------
__global__ __launch_bounds__(256)
void prep0(const float* __restrict__ u, const float* __restrict__ bw0,
           u16* __restrict__ ubf, u16* __restrict__ bw0t)
{
    __shared__ float tile[64][65];
    const int bid = blockIdx.x, tid = threadIdx.x;
    if (bid < 128) {
        int i = (bid * 256 + tid) * 8;
        float4 a = *(const float4*)&u[i];
        float4 b = *(const float4*)&u[i + 4];
        uint4 o;
        o.x = (u32)f2bf(a.x) | ((u32)f2bf(a.y) << 16);
        o.y = (u32)f2bf(a.z) | ((u32)f2bf(a.w) << 16);
        o.z = (u32)f2bf(b.x) | ((u32)f2bf(b.y) << 16);
        o.w = (u32)f2bf(b.z) | ((u32)f2bf(b.w) << 16);
        *(uint4*)&ubf[i] = o;
        return;
    }
    const int idx = bid - 128;                 // 32 tiles: rb in {0,64}, cb 16x
    const int rb = (idx >> 4) * 64, cb = (idx & 15) * 64;
    for (int i = tid; i < 64 * 64; i += 256) {
        int r = i >> 6, c = i & 63;
        tile[r][c] = bw0[(size_t)(rb + r) * 1024 + cb + c];
    }
    __syncthreads();
    for (int i = tid; i < 64 * 64; i += 256) {
        int c = i >> 6, r = i & 63;
        bw0t[(size_t)(cb + c) * 128 + rb + r] = f2bf(tile[r][c]);
    }
}

// ---------------------------------------------------------------------------
// Fused branch GEMM + horizontal prep.
// blocks [0,512): 64x64 GEMM  C = tanh(A @ Bt^T + bias)   (bn=(b&15)*64, bm=(b>>4)*64)
// mode 0/1/2, blocks [512,768): transpose xsrc(1024x1024) -> xdst[n][k]
// mode 2, blocks [768,1281):    BWt[n][k]=(bw4@W1)[k][n] f32-parallel; block 1280: bz
// mode 3, blocks [512,1028):    gather trunk Bt[layer][n][p] (32-row tiles)
// ---------------------------------------------------------------------------
__global__ __launch_bounds__(256, 2)
void gemm_fused(const u16* __restrict__ A, int lda,
                const u16* __restrict__ Bt, int ldb,
                const float* __restrict__ bias,
                u16* __restrict__ Cout, int ldc, int K, int mode,
                const float* __restrict__ xsrc, u16* __restrict__ xdst,
                const float* __restrict__ bw4, const float* __restrict__ bb4,
                const float* __restrict__ W1, u16* __restrict__ BWt,
                float* __restrict__ bz,
                const float* __restrict__ W2, u16* __restrict__ Btb)
{
    __shared__ __align__(16) char lds[16640];
    const int bid = blockIdx.x, tid = threadIdx.x;

    if (bid < 512) {                           // ================= GEMM
        u16 (*As)[64 * 32] = (u16(*)[64 * 32])lds;
        u16 (*Bs)[64 * 32] = (u16(*)[64 * 32])(lds + 8192);
        const int lane = tid & 63, wid = tid >> 6;
        const int wr = wid >> 1, wc = wid & 1;
        const int bn = (bid & 15) * 64, bm = (bid >> 4) * 64;
        const int NT = K >> 5;
        const int arow = tid >> 2, ck = tid & 3;
        const u16* aSrc = A + (size_t)(bm + arow) * lda + (ck ^ (arow & 3)) * 8;
        const u16* bSrc = Bt + (size_t)(bn + arow) * ldb + (ck ^ (arow & 3)) * 8;
        f32x4 acc[2][2] = {};

        auto STAGE = [&](int buf, int t) {
            const int k0 = t << 5;
            gload_lds16(aSrc + k0, (char*)As[buf] + wid * 1024);
            gload_lds16(bSrc + k0, (char*)Bs[buf] + wid * 1024);
        };
        auto COMPUTE = [&](int buf) {
            s16x8 a[2], b[2];
            #pragma unroll
            for (int mi = 0; mi < 2; ++mi) {
                int row = wr * 32 + mi * 16 + (lane & 15);
                int s = (lane >> 4) ^ (row & 3);
                a[mi] = *(const s16x8*)&As[buf][row * 32 + s * 8];
            }
            #pragma unroll
            for (int ni = 0; ni < 2; ++ni) {
                int n = wc * 32 + ni * 16 + (lane & 15);
                int s = (lane >> 4) ^ (n & 3);
                b[ni] = *(const s16x8*)&Bs[buf][n * 32 + s * 8];
            }
            #pragma unroll
            for (int mi = 0; mi < 2; ++mi)
            #pragma unroll
            for (int ni = 0; ni < 2; ++ni)
                acc[mi][ni] = MFMA(a[mi], b[ni], acc[mi][ni]);
        };

        STAGE(0, 0);
        __syncthreads();
        for (int t = 0; t < NT; ++t) {
            if (t + 1 < NT) STAGE((t + 1) & 1, t + 1);
            COMPUTE(t & 1);
            __syncthreads();
        }
        #pragma unroll
        for (int mi = 0; mi < 2; ++mi)
        #pragma unroll
        for (int ni = 0; ni < 2; ++ni) {
            const int col = bn + wc * 32 + ni * 16 + (lane & 15);
            const float bv = bias[col];
            #pragma unroll
            for (int jj = 0; jj < 4; ++jj) {
                const int row = bm + wr * 32 + mi * 16 + (lane >> 4) * 4 + jj;
                Cout[(size_t)row * ldc + col] = f2bf(fast_tanh(acc[mi][ni][jj] + bv));
            }
        }
    } else if (mode <= 2 && bid < 768) {       // ================= transpose 1024^2
        float (*tile)[65] = (float(*)[65])lds;
        const int idx = bid - 512;
        const int rb = (idx >> 4) * 64, cb = (idx & 15) * 64;
        for (int i = tid; i < 64 * 64; i += 256) {
            int r = i >> 6, c = i & 63;
            tile[r][c] = xsrc[(size_t)(rb + r) * 1024 + cb + c];
        }
        __syncthreads();
        for (int i = tid; i < 64 * 64; i += 256) {
            int c = i >> 6, r = i & 63;
            xdst[(size_t)(cb + c) * 1024 + rb + r] = f2bf(tile[r][c]);
        }
    } else if (mode == 2) {                    // ================= BW / bz
        const int lb = bid - 768;              // 0..512
        const int n = tid & 63, jc = tid >> 6;
        if (lb == 512) {
            float (*sh1)[64] = (float(*)[64])lds;
            float a = 0.f;
            for (int j = jc * 256; j < jc * 256 + 256; ++j)
                a = fmaf(bb4[j], W1[j * 64 + n], a);
            sh1[jc][n] = a;
            __syncthreads();
            if (tid < 64)
                bz[tid] = sh1[0][tid] + sh1[1][tid] + sh1[2][tid] + sh1[3][tid];
            return;
        }
        float (*sh)[2][64] = (float(*)[2][64])lds;     // [4][2][64]
        const int k0 = lb * 2;
        float a0 = 0.f, a1 = 0.f;
        for (int j = jc * 256; j < jc * 256 + 256; ++j) {
            float w = W1[j * 64 + n];
            a0 = fmaf(bw4[(size_t)k0 * 1024 + j], w, a0);
            a1 = fmaf(bw4[(size_t)(k0 + 1) * 1024 + j], w, a1);
        }
        sh[jc][0][n] = a0; sh[jc][1][n] = a1;
        __syncthreads();
        if (tid < 128) {
            int kk = tid >> 6, nn = tid & 63;
            float s = sh[0][kk][nn] + sh[1][kk][nn] + sh[2][kk][nn] + sh[3][kk][nn];
            BWt[(size_t)nn * 1024 + k0 + kk] = f2bf(s);
        }
    } else {                                   // ================= gather trunk (mode 3)
        float (*tile)[130] = (float(*)[130])lds;       // [32][130] = 16.6 KB
        const int idx = bid - 512;             // 0..515
        const int layer = idx / 258, pbi = idx % 258;
        u16* Btd = Btb + (size_t)layer * 128 * 8256;
        const int colbase = layer ? 16896 : 384, biasbase = layer ? 16768 : 256;
        const int pb = pbi * 32;
        for (int i = tid; i < 32 * 128; i += 256) {
            int p = pb + (i >> 7), n = i & 127;
            float v = (p < 8192)
                ? W2[(size_t)(p & 63) * LDP + colbase + (size_t)(p >> 6) * 128 + n]
                : W2[(size_t)(p - 8192) * LDP + biasbase + n];
            tile[i >> 7][n] = v;
        }
        __syncthreads();
        for (int i = tid; i < 32 * 128; i += 256) {
            int n = i >> 5, dp = i & 31;
            Btd[(size_t)n * 8256 + pb + dp] = f2bf(tile[dp][n]);
        }
    }
}

// ---------------------------------------------------------------------------
// z-GEMM: zc[kz][2048][64] = actB @ BWt^T partials, SK=8, 64x64 tile
// ---------------------------------------------------------------------------
__global__ __launch_bounds__(256, 2)
void zgemm(const u16* __restrict__ A, const u16* __restrict__ Bt,
           float* __restrict__ zc)
{
    __shared__ __align__(16) u16 As[2][64 * 32];
    __shared__ __align__(16) u16 Bs[2][64 * 32];
    const int tid = threadIdx.x, lane = tid & 63, wid = tid >> 6;
    const int wr = wid >> 1, wc = wid & 1;
    const int bm = blockIdx.y * 64, kz = blockIdx.z;
    const int t0 = kz * 4, nt = 4;
    const int arow = tid >> 2, ck = tid & 3;
    const u16* aSrc = A + (size_t)(bm + arow) * 1024 + (ck ^ (arow & 3)) * 8;
    const u16* bSrc = Bt + (size_t)arow * 1024 + (ck ^ (arow & 3)) * 8;
    f32x4 acc[2][2] = {};

    auto STAGE = [&](int buf, int t) {
        const int k0 = t << 5;
        gload_lds16(aSrc + k0, (char*)As[buf] + wid * 1024);
        gload_lds16(bSrc + k0, (char*)Bs[buf] + wid * 1024);
    };
    auto COMPUTE = [&](int buf) {
        s16x8 a[2];
        #pragma unroll
        for (int mi = 0; mi < 2; ++mi) {
            int row = wr * 32 + mi * 16 + (lane & 15);
            int s = (lane >> 4) ^ (row & 3);
            a[mi] = *(const s16x8*)&As[buf][row * 32 + s * 8];
        }
        #pragma unroll
        for (int ni = 0; ni < 2; ++ni) {
            int n = wc * 32 + ni * 16 + (lane & 15);
            int s = (lane >> 4) ^ (n & 3);
            s16x8 b = *(const s16x8*)&Bs[buf][n * 32 + s * 8];
            #pragma unroll
            for (int mi = 0; mi < 2; ++mi)
                acc[mi][ni] = MFMA(a[mi], b, acc[mi][ni]);
        }
    };

    STAGE(0, t0);
    __syncthreads();
    for (int t = 0; t < nt; ++t) {
        if (t + 1 < nt) STAGE((t + 1) & 1, t0 + t + 1);
        COMPUTE(t & 1);
        __syncthreads();
    }
    #pragma unroll
    for (int mi = 0; mi < 2; ++mi)
    #pragma unroll
    for (int ni = 0; ni < 2; ++ni) {
        const int col = wc * 32 + ni * 16 + (lane & 15);
        #pragma unroll
        for (int jj = 0; jj < 4; ++jj) {
            const int row = bm + wr * 32 + mi * 16 + (lane >> 4) * 4 + jj;
            zc[((size_t)kz * 2048 + row) * 64 + col] = acc[mi][ni][jj];
        }
    }
}

// ---------------------------------------------------------------------------
// Fused: reduce_z (+bz) -> z bf16 ; trunk L1 (K=64, VALU) -> h1 bf16
// 128 blocks x 16 rows
// ---------------------------------------------------------------------------
__global__ __launch_bounds__(256)
void z_l1_h1(const float* __restrict__ zc, const float* __restrict__ bz,
             const float* __restrict__ W2, const float* __restrict__ t,
             u16* __restrict__ z, u16* __restrict__ h1)
{
    __shared__ float zsh[16][64];
    const int rb = blockIdx.x * 16;
    #pragma unroll
    for (int ii = 0; ii < 4; ++ii) {
        int e = ii * 256 + threadIdx.x;
        int r = e >> 6, k = e & 63;
        size_t off = (size_t)(rb + r) * 64 + k;
        float s = bz[k];
        #pragma unroll
        for (int sk = 0; sk < 8; ++sk) s += zc[(size_t)sk * 2048 * 64 + off];
        zsh[r][k] = s;
        z[off] = f2bf(s);
    }
    __syncthreads();
    const int o = threadIdx.x & 127;
    const int rh = (threadIdx.x >> 7) * 8;
    float acc_a[8] = {}, acc_b[8] = {};
    for (int k = 0; k < 64; ++k) {
        float wa = W2[(size_t)k * LDP + o];
        float wb = W2[(size_t)k * LDP + 128 + o];
        #pragma unroll
        for (int r = 0; r < 8; ++r) {
            float zv = zsh[rh + r][k];
            acc_a[r] = fmaf(zv, wa, acc_a[r]);
            acc_b[r] = fmaf(zv, wb, acc_b[r]);
        }
    }
    #pragma unroll
    for (int r = 0; r < 8; ++r) {
        int b = rb + rh + r;
        h1[b * 128 + o] = f2bf(fast_tanh(t[b] * acc_b[r] + acc_a[r]));
    }
}

// ---------------------------------------------------------------------------
// Trunk GEMM: 512 threads / 8 waves (4Mx2N), 128x128 tile, SK=16.
// A generated on the fly: p<8192: h[b,p>>6]*z[b,p&63]; else z[b,p-8192].
// ---------------------------------------------------------------------------
__global__ __launch_bounds__(512, 2)
void trunk128(const u16* __restrict__ h, const u16* __restrict__ z,
              const u16* __restrict__ Bt, float* __restrict__ Cp)
{
    constexpr int NT = 258, SKT = 16;
    __shared__ __align__(16) u16 As[2][128 * 32];
    __shared__ __align__(16) u16 Bs[2][128 * 32];
    const int tid = threadIdx.x, lane = tid & 63, wid = tid >> 6;
    const int wr = wid >> 1, wc = wid & 1;
    const int bm = blockIdx.x * 128, kz = blockIdx.y;
    const int t0 = (NT * kz) / SKT, t1 = (NT * (kz + 1)) / SKT;
    const int arow = tid >> 2, ck = tid & 3;
    const int b = bm + arow;
    const s16x8 zlo = *(const s16x8*)&z[b * 64 + ck * 8];
    const s16x8 zhi = *(const s16x8*)&z[b * 64 + 32 + ck * 8];
    const int slot = (ck ^ (arow & 3)) * 8;
    f32x4 acc[2][4] = {};

    auto STAGE = [&](int buf, int t) {
        const int p0 = t << 5;
        gload_lds16(Bt + (size_t)arow * 8256 + p0 + (ck ^ (arow & 3)) * 8,
                    (char*)Bs[buf] + wid * 1024);
        const s16x8 zv = (p0 & 32) ? zhi : zlo;
        u16 o8[8];
        if (p0 < 8192) {
            const float hf = bf2f(h[b * 128 + (p0 >> 6)]);
            #pragma unroll
            for (int j = 0; j < 8; ++j) o8[j] = f2bf(hf * bf2f((u16)zv[j]));
        } else {
            #pragma unroll
            for (int j = 0; j < 8; ++j) o8[j] = (u16)zv[j];
        }
        *(s16x8*)&As[buf][arow * 32 + slot] = *(s16x8*)o8;
    };
    auto COMPUTE = [&](int buf) {
        s16x8 a[2], bb[4];
        #pragma unroll
        for (int mi = 0; mi < 2; ++mi) {
            int row = wr * 32 + mi * 16 + (lane & 15);
            int s = (lane >> 4) ^ (row & 3);
            a[mi] = *(const s16x8*)&As[buf][row * 32 + s * 8];
        }
        #pragma unroll
        for (int ni = 0; ni < 4; ++ni) {
            int n = wc * 64 + ni * 16 + (lane & 15);
            int s = (lane >> 4) ^ (n & 3);
            bb[ni] = *(const s16x8*)&Bs[buf][n * 32 + s * 8];
        }
        #pragma unroll
        for (int mi = 0; mi < 2; ++mi)
        #pragma unroll
        for (int ni = 0; ni < 4; ++ni)
            acc[mi][ni] = MFMA(a[mi], bb[ni], acc[mi][ni]);
    };

    STAGE(0, t0);
    __syncthreads();
    const int nt = t1 - t0;
    for (int t = 0; t < nt; ++t) {
        if (t + 1 < nt) STAGE((t + 1) & 1, t0 + t + 1);
        COMPUTE(t & 1);
        __syncthreads();
    }

    #pragma unroll
    for (int mi = 0; mi < 2; ++mi)
    #pragma unroll
    for (int ni = 0; ni < 4; ++ni) {
        const int col = wc * 64 + ni * 16 + (lane & 15);
        #pragma unroll
        for (int jj = 0; jj < 4; ++jj) {
            const int row = bm + wr * 32 + mi * 16 + (lane >> 4) * 4 + jj;
            Cp[((size_t)kz * 2048 + row) * 128 + col] = acc[mi][ni][jj];
        }
    }
}

// ---------------------------------------------------------------------------
__global__ __launch_bounds__(256)
void reduce_tanh(const float* __restrict__ Cp, u16* __restrict__ hout) {
    const int idx = blockIdx.x * 256 + threadIdx.x;
    const size_t S = (size_t)2048 * 128;
    float s = 0.f;
    #pragma unroll
    for (int k = 0; k < 16; ++k) s += Cp[idx + k * S];
    hout[idx] = f2bf(fast_tanh(s));
}

// layer-3 reduce+tanh fused with trunk L4 + final combine
__global__ __launch_bounds__(256)
void reduce_out(const float* __restrict__ Cp, const u16* __restrict__ z,
                const float* __restrict__ W2, const float* __restrict__ t,
                const float* __restrict__ u, float* __restrict__ out)
{
    __shared__ float sh[4][128];
    const int wv = threadIdx.x >> 6, l = threadIdx.x & 63;
    const int b = blockIdx.x * 4 + wv;
    const size_t S = (size_t)2048 * 128;
    #pragma unroll
    for (int e = l; e < 128; e += 64) {
        float s = 0.f;
        #pragma unroll
        for (int k = 0; k < 16; ++k) s += Cp[k * S + (size_t)b * 128 + e];
        sh[wv][e] = fast_tanh(s);
    }
    __syncthreads();
    const float* wrow = &W2[(size_t)l * LDP + 33280];
    float acc = wrow[0];
    #pragma unroll 8
    for (int i = 0; i < 128; ++i) acc = fmaf(sh[wv][i], wrow[1 + i], acc);
    float p = bf2f(z[b * 64 + l]) * acc;
    #pragma unroll
    for (int off = 32; off > 0; off >>= 1) p += __shfl_down(p, off);
    if (l == 0) out[b] = u[b * 128] + t[b] * p;
}

// ---------------------------------------------------------------------------
extern "C" void kernel_launch(void* const* d_in, const int* in_sizes, int n_in,
                              void* d_out, int out_size, void* d_ws, size_t ws_size,
                              hipStream_t stream)
{
    const float* t   = (const float*)d_in[0];
    const float* u   = (const float*)d_in[1];
    const float* bw0 = (const float*)d_in[2];
    const float* bb0 = (const float*)d_in[3];
    const float* bw1 = (const float*)d_in[4];
    const float* bb1 = (const float*)d_in[5];
    const float* bw2 = (const float*)d_in[6];
    const float* bb2 = (const float*)d_in[7];
    const float* bw3 = (const float*)d_in[8];
    const float* bb3 = (const float*)d_in[9];
    const float* bw4 = (const float*)d_in[10];
    const float* bb4 = (const float*)d_in[11];
    const float* W1  = (const float*)d_in[12];
    const float* W2  = (const float*)d_in[13];
    float* out = (float*)d_out;

    // ---- workspace layout (bytes)
    char* base = (char*)d_ws;
    u16*   bw1t = (u16*)(base);                  // 2 MB
    u16*   bw2t = (u16*)(base + 2097152);        // 2 MB
    u16*   bw3t = (u16*)(base + 4194304);        // 2 MB
    u16*   actA = (u16*)(base + 6291456);        // 4 MB
    u16*   actB = (u16*)(base + 10485760);       // 4 MB
    u16*   ubf  = (u16*)(base + 14680064);       // 512 KB
    u16*   bw0t = (u16*)(base + 15204352);       // 256 KB
    u16*   BWt  = (u16*)(base + 15499264);       // 128 KB
    float* bz   = (float*)(base + 15630336);     // 256 B
    u16*   z    = (u16*)(base + 16777216);       // 256 KB
    u16*   h1   = (u16*)(base + 17039360);       // 512 KB
    u16*   h2   = (u16*)(base + 17563648);       // 512 KB
    u16*   Bt   = (u16*)(base + 18087936);       // 4,227,072 (2 layers)
    // overlays:
    float* zc = (float*)(base);                  // 4 MB   (zgemm .. z_l1_h1)
    float* Cp = (float*)(base);                  // 16.78 MB (trunk partials)

    dim3 blk(256);
    // ---- prep0 (ubf + bw0t only)
    prep0<<<160, blk, 0, stream>>>(u, bw0, ubf, bw0t);

    // ---- branch MLP with horizontally-fused prep
    gemm_fused<<<768, blk, 0, stream>>>(                       // L0 + T(bw1)
        ubf, 128, bw0t, 128, bb0, actA, 1024, 128, 0,
        bw1, bw1t, bw4, bb4, W1, BWt, bz, W2, Bt);
    gemm_fused<<<768, blk, 0, stream>>>(                       // L1 + T(bw2)
        actA, 1024, bw1t, 1024, bb1, actB, 1024, 1024, 1,
        bw2, bw2t, bw4, bb4, W1, BWt, bz, W2, Bt);
    gemm_fused<<<1281, blk, 0, stream>>>(                      // L2 + T(bw3) + BW + bz
        actB, 1024, bw2t, 1024, bb2, actA, 1024, 1024, 2,
        bw3, bw3t, bw4, bb4, W1, BWt, bz, W2, Bt);
    gemm_fused<<<1028, blk, 0, stream>>>(                      // L3 + gather Bt
        actA, 1024, bw3t, 1024, bb3, actB, 1024, 1024, 3,
        nullptr, nullptr, bw4, bb4, W1, BWt, bz, W2, Bt);
    // ---- z partials (SK=8)
    zgemm<<<dim3(1, 32, 8), blk, 0, stream>>>(actB, BWt, zc);
    // ---- fused reduce_z + trunk L1 + h1
    z_l1_h1<<<128, blk, 0, stream>>>(zc, bz, W2, t, z, h1);
    // ---- trunk layers 2,3 (128x128 tiles, 8 waves, split-K=16)
    trunk128<<<dim3(16, 16), dim3(512), 0, stream>>>(h1, z, Bt, Cp);
    reduce_tanh<<<1024, blk, 0, stream>>>(Cp, h2);
    trunk128<<<dim3(16, 16), dim3(512), 0, stream>>>(h2, z, Bt + (size_t)128 * 8256, Cp);
    // ---- layer-3 reduce + trunk L4 + combine
    reduce_out<<<512, blk, 0, stream>>>(Cp, z, W2, t, u, out);
}